// Round 10
// baseline (245.770 us; speedup 1.0000x reference)
//
#include <hip/hip_runtime.h>

#define C 128
#define MAXNB 1024
typedef unsigned int uint;
typedef unsigned short ushort;
typedef __attribute__((ext_vector_type(4))) float f32x4;
typedef __attribute__((ext_vector_type(8))) short bf16x8;

__device__ __forceinline__ float blo(uint u) { return __uint_as_float(u << 16); }
__device__ __forceinline__ float bhi(uint u) { return __uint_as_float(u & 0xFFFF0000u); }
// pack two f32 -> (bf16(LO) | bf16(HI)<<16), round-half-up
#define PACKBF(LO, HI) __builtin_amdgcn_perm(__float_as_uint(HI) + 0x8000u, \
                                             __float_as_uint(LO) + 0x8000u, 0x07060302u)

// ---------------- A1: per-block bucket histogram (no global atomics) ----------------
__global__ __launch_bounds__(256) void k_hist(const int* __restrict__ col,
                                              int* __restrict__ counts,
                                              int nE, int NB, int NBLK) {
    __shared__ int hist[MAXNB];
    const int t = threadIdx.x, blk = blockIdx.x;
    for (int i = t; i < NB; i += 256) hist[i] = 0;
    __syncthreads();
    const int base = blk * 2048;
    for (int k = 0; k < 8; ++k) {
        int e = base + k * 256 + t;
        if (e < nE) atomicAdd(&hist[col[e] >> 7], 1);
    }
    __syncthreads();
    for (int i = t; i < NB; i += 256) counts[i * NBLK + blk] = hist[i];
}

// ---------------- exclusive scan of counts[scanN], 3 kernels ----------------
__global__ __launch_bounds__(256) void k_scan1(int* __restrict__ counts,
                                               int* __restrict__ bsum, int scanN) {
    __shared__ int s[256];
    int t = threadIdx.x;
    int i = blockIdx.x * 256 + t;
    int v = (i < scanN) ? counts[i] : 0;
    s[t] = v;
    __syncthreads();
    for (int d = 1; d < 256; d <<= 1) {
        int a = (t >= d) ? s[t - d] : 0;
        __syncthreads();
        s[t] += a;
        __syncthreads();
    }
    if (i < scanN) counts[i] = s[t] - v;
    if (t == 255) bsum[blockIdx.x] = s[255];
}

__global__ __launch_bounds__(256) void k_scan2(int* __restrict__ bsum, int nb) {
    __shared__ int s[256];
    __shared__ int carry;
    int t = threadIdx.x;
    if (t == 0) carry = 0;
    __syncthreads();
    int nch = (nb + 255) / 256;
    for (int c = 0; c < nch; ++c) {
        int i = c * 256 + t;
        int v = (i < nb) ? bsum[i] : 0;
        s[t] = v;
        __syncthreads();
        for (int d = 1; d < 256; d <<= 1) {
            int a = (t >= d) ? s[t - d] : 0;
            __syncthreads();
            s[t] += a;
            __syncthreads();
        }
        int cb = carry;
        if (i < nb) bsum[i] = s[t] - v + cb;
        int tot = s[255];
        __syncthreads();
        if (t == 0) carry = cb + tot;
        __syncthreads();
    }
}

__global__ __launch_bounds__(256) void k_scan3(int* __restrict__ counts,
                                               const int* __restrict__ bsum,
                                               int* __restrict__ bstart,
                                               int scanN, int NBLK, int NB, int nE) {
    int i = blockIdx.x * 256 + threadIdx.x;
    if (i >= scanN) return;
    int v = counts[i] + bsum[i >> 8];
    counts[i] = v;
    if (i % NBLK == 0) {
        bstart[i / NBLK] = v;
        if (i == 0) bstart[NB] = nE;
    }
}

// ---------------- A2: bin edges into bucket regions (no global atomics) ----------------
__global__ __launch_bounds__(256) void k_scatter(const int* __restrict__ ei,
                                                 const float* __restrict__ ew,
                                                 const int* __restrict__ counts,
                                                 int2* __restrict__ ev2,
                                                 int nE, int NB, int NBLK) {
    __shared__ int base_l[MAXNB];
    __shared__ int cnt_l[MAXNB];
    const int t = threadIdx.x, blk = blockIdx.x;
    for (int i = t; i < NB; i += 256) {
        base_l[i] = counts[i * NBLK + blk];
        cnt_l[i] = 0;
    }
    __syncthreads();
    const int base = blk * 2048;
    for (int k = 0; k < 8; ++k) {
        int e = base + k * 256 + t;
        if (e >= nE) continue;
        int c = ei[nE + e];
        int row = ei[e];
        int b = c >> 7;
        int pos = base_l[b] + atomicAdd(&cnt_l[b], 1);
        ev2[pos] = make_int2(((c & 127) << 25) | row, __float_as_int(ew[e]));
    }
}

// ---------------- B: per-bucket counting sort + degree ----------------
__global__ __launch_bounds__(256) void k_sortdeg(const int2* __restrict__ ev2,
                                                 const int* __restrict__ bstart,
                                                 int2* __restrict__ evs,
                                                 int* __restrict__ offs,
                                                 float* __restrict__ dis,
                                                 int n, int nE) {
    __shared__ int cnt[128];
    __shared__ float wsum[128];
    __shared__ int cur[128];
    __shared__ int sc[128];
    const int t = threadIdx.x, b = blockIdx.x;
    if (t < 128) { cnt[t] = 0; wsum[t] = 0.f; }
    __syncthreads();
    const int s = bstart[b], e = bstart[b + 1];
    for (int i = s + t; i < e; i += 256) {
        int2 E = ev2[i];
        int cl = (uint)E.x >> 25;
        atomicAdd(&cnt[cl], 1);
        atomicAdd(&wsum[cl], __int_as_float(E.y));
    }
    __syncthreads();
    if (t < 128) sc[t] = cnt[t];
    __syncthreads();
    for (int d = 1; d < 128; d <<= 1) {
        int v = 0;
        if (t < 128 && t >= d) v = sc[t - d];
        __syncthreads();
        if (t < 128) sc[t] += v;
        __syncthreads();
    }
    if (t < 128) {
        int col = (b << 7) + t;
        int base = s + sc[t] - cnt[t];
        cur[t] = base;
        if (col < n) {
            offs[col] = base;
            dis[col] = rsqrtf(1.0f + wsum[t]);
        }
    }
    if (b == 0 && t == 0) offs[n] = nE;
    __syncthreads();
    for (int i = s + t; i < e; i += 256) {
        int2 E = ev2[i];
        int cl = (uint)E.x >> 25;
        int pos = atomicAdd(&cur[cl], 1);
        evs[pos] = make_int2(E.x & 0x1FFFFFF, E.y);
    }
}

// ---------------- xb' = bf16(dis[r] * x[r]) ----------------
__global__ __launch_bounds__(256) void k_cvt(const float4* __restrict__ x4,
                                             const float* __restrict__ dis,
                                             ushort4* __restrict__ xb4, long total4) {
    long i = (long)blockIdx.x * 256 + threadIdx.x;
    if (i >= total4) return;
    float d = dis[i >> 5];
    float4 v = x4[i];
    ushort4 r;
#define RNE(OUT, F)                                                     \
    {                                                                   \
        uint u = __float_as_uint((F) * d);                              \
        OUT = (ushort)((u + 0x7FFFu + ((u >> 16) & 1u)) >> 16);         \
    }
    RNE(r.x, v.x) RNE(r.y, v.y) RNE(r.z, v.z) RNE(r.w, v.w)
#undef RNE
    xb4[i] = r;
}

// ---------------- WbT[o][k] = bf16(W[k][o]) ----------------
__global__ __launch_bounds__(256) void k_wcvt(const float* __restrict__ W,
                                              ushort* __restrict__ WbT) {
    int idx = blockIdx.x * 256 + threadIdx.x;   // 16384 total
    int k = idx >> 7, o = idx & 127;
    uint u = __float_as_uint(W[idx]);
    WbT[o * 128 + k] = (ushort)((u + 0x7FFFu + ((u >> 16) & 1u)) >> 16);
}

// ---------------- segment aggregation -> bf16 agg ----------------
// aggb[col] = bf16( dis[col] * ( xb'[col] + sum_e w_e * xb'[row_e] ) )
__global__ __launch_bounds__(256) void k_segagg(const ushort* __restrict__ xb,
                                                const int2* __restrict__ ev,
                                                const int* __restrict__ offs,
                                                const float* __restrict__ dis,
                                                ushort* __restrict__ aggb, int n) {
    const int lane = threadIdx.x & 15;   // 0..15
    const int sub  = threadIdx.x >> 4;   // 0..15
    const int col  = blockIdx.x * 16 + sub;
    if (col >= n) return;

    uint4 sv = *(const uint4*)(xb + (size_t)col * C + lane * 8);
    float acc[8] = {blo(sv.x), bhi(sv.x), blo(sv.y), bhi(sv.y),
                    blo(sv.z), bhi(sv.z), blo(sv.w), bhi(sv.w)};

    int i = offs[col];
    const int end = offs[col + 1];

#define EDGE(E, V)                                                        \
    {                                                                     \
        float nw = __int_as_float(E.y);                                   \
        acc[0] = fmaf(nw, blo(V.x), acc[0]);                              \
        acc[1] = fmaf(nw, bhi(V.x), acc[1]);                              \
        acc[2] = fmaf(nw, blo(V.y), acc[2]);                              \
        acc[3] = fmaf(nw, bhi(V.y), acc[3]);                              \
        acc[4] = fmaf(nw, blo(V.z), acc[4]);                              \
        acc[5] = fmaf(nw, bhi(V.z), acc[5]);                              \
        acc[6] = fmaf(nw, blo(V.w), acc[6]);                              \
        acc[7] = fmaf(nw, bhi(V.w), acc[7]);                              \
    }
#define GATH(K) uint4 v##K = *(const uint4*)(xb + (size_t)e##K.x * C + lane * 8);

    for (; i + 8 <= end; i += 8) {
        int2 e0 = ev[i],     e1 = ev[i + 1], e2 = ev[i + 2], e3 = ev[i + 3];
        int2 e4 = ev[i + 4], e5 = ev[i + 5], e6 = ev[i + 6], e7 = ev[i + 7];
        GATH(0) GATH(1) GATH(2) GATH(3) GATH(4) GATH(5) GATH(6) GATH(7)
        EDGE(e0, v0) EDGE(e1, v1) EDGE(e2, v2) EDGE(e3, v3)
        EDGE(e4, v4) EDGE(e5, v5) EDGE(e6, v6) EDGE(e7, v7)
    }
    for (; i + 2 <= end; i += 2) {
        int2 e0 = ev[i], e1 = ev[i + 1];
        GATH(0) GATH(1)
        EDGE(e0, v0) EDGE(e1, v1)
    }
    if (i < end) {
        int2 e0 = ev[i];
        GATH(0)
        EDGE(e0, v0)
    }
#undef GATH
#undef EDGE

    float d = dis[col];
    uint4 r;
    r.x = PACKBF(d * acc[0], d * acc[1]);
    r.y = PACKBF(d * acc[2], d * acc[3]);
    r.z = PACKBF(d * acc[4], d * acc[5]);
    r.w = PACKBF(d * acc[6], d * acc[7]);
    *(uint4*)(aggb + (size_t)col * C + lane * 8) = r;
}

// ---------------- MFMA GEMM: out = aggb @ W, BN partial stats fused ----------------
// A = W^T tile, B = bf16 agg rows (direct 16B loads). D transposed: lane owns
// 4 consecutive channels of one row per ot. Stats: shfl-reduce over the 16-lane
// row group, per-block partials to part[] (no atomics).
__global__ __launch_bounds__(256, 4) void k_gemm(const ushort* __restrict__ aggb,
                                                 float* __restrict__ out,
                                                 const ushort* __restrict__ WbT,
                                                 float* __restrict__ part, int n) {
    const int t = threadIdx.x;
    const int lane = t & 63;
    const int wv = t >> 6;
    const int lr = lane & 15;
    const int lk = lane >> 4;
    const long m = (long)blockIdx.x * 64 + wv * 16 + lr;
    const bool inr = m < (long)n;

    bf16x8 b0, b1, b2, b3;
    if (inr) {
        const bf16x8* p = (const bf16x8*)(aggb + (size_t)m * C + lk * 8);
        b0 = p[0];   // k = lk*8
        b1 = p[4];   // k = 32 + lk*8
        b2 = p[8];   // k = 64 + lk*8
        b3 = p[12];  // k = 96 + lk*8
    } else {
        b0 = b1 = b2 = b3 = (bf16x8){0, 0, 0, 0, 0, 0, 0, 0};
    }

    f32x4 acc[8];
#pragma unroll
    for (int ot = 0; ot < 8; ++ot) acc[ot] = (f32x4){0.f, 0.f, 0.f, 0.f};

#pragma unroll 2
    for (int ot = 0; ot < 8; ++ot) {
        const ushort* wp = WbT + (ot * 16 + lr) * 128 + lk * 8;
        bf16x8 a0 = *(const bf16x8*)(wp);
        bf16x8 a1 = *(const bf16x8*)(wp + 32);
        bf16x8 a2 = *(const bf16x8*)(wp + 64);
        bf16x8 a3 = *(const bf16x8*)(wp + 96);
        acc[ot] = __builtin_amdgcn_mfma_f32_16x16x32_bf16(a0, b0, acc[ot], 0, 0, 0);
        acc[ot] = __builtin_amdgcn_mfma_f32_16x16x32_bf16(a1, b1, acc[ot], 0, 0, 0);
        acc[ot] = __builtin_amdgcn_mfma_f32_16x16x32_bf16(a2, b2, acc[ot], 0, 0, 0);
        acc[ot] = __builtin_amdgcn_mfma_f32_16x16x32_bf16(a3, b3, acc[ot], 0, 0, 0);
    }

    // ---- stores + per-ot stats reduce over the 16-lane row group ----
    __shared__ float lds_s[4][128];
    __shared__ float lds_q[4][128];
    float* orow = out + (size_t)m * C + lk * 4;
#pragma unroll
    for (int ot = 0; ot < 8; ++ot) {
        if (inr)
            *(float4*)(orow + ot * 16) =
                make_float4(acc[ot][0], acc[ot][1], acc[ot][2], acc[ot][3]);
        float s0 = acc[ot][0], s1 = acc[ot][1], s2 = acc[ot][2], s3 = acc[ot][3];
        float q0 = s0 * s0, q1 = s1 * s1, q2 = s2 * s2, q3 = s3 * s3;
#pragma unroll
        for (int msk = 1; msk < 16; msk <<= 1) {
            s0 += __shfl_xor(s0, msk); q0 += __shfl_xor(q0, msk);
            s1 += __shfl_xor(s1, msk); q1 += __shfl_xor(q1, msk);
            s2 += __shfl_xor(s2, msk); q2 += __shfl_xor(q2, msk);
            s3 += __shfl_xor(s3, msk); q3 += __shfl_xor(q3, msk);
        }
        if (lr == 0) {
            int ch = ot * 16 + lk * 4;
            lds_s[wv][ch + 0] = s0; lds_q[wv][ch + 0] = q0;
            lds_s[wv][ch + 1] = s1; lds_q[wv][ch + 1] = q1;
            lds_s[wv][ch + 2] = s2; lds_q[wv][ch + 2] = q2;
            lds_s[wv][ch + 3] = s3; lds_q[wv][ch + 3] = q3;
        }
    }
    __syncthreads();
    float ps;
    if (t < 128)
        ps = lds_s[0][t] + lds_s[1][t] + lds_s[2][t] + lds_s[3][t];
    else {
        int c = t - 128;
        ps = lds_q[0][c] + lds_q[1][c] + lds_q[2][c] + lds_q[3][c];
    }
    part[(size_t)blockIdx.x * 256 + t] = ps;
}

__global__ __launch_bounds__(256) void k_finish(const float* __restrict__ part,
                                                float* __restrict__ sums, int nblk) {
    int t = threadIdx.x;
    float s = 0.f;
    for (int b = blockIdx.x; b < nblk; b += gridDim.x) s += part[(size_t)b * 256 + t];
    atomicAdd(&sums[t], s);
}

// ---------------- BN apply + ReLU (in place) ----------------
__global__ __launch_bounds__(256) void k_apply(float* __restrict__ out,
                                               const float* __restrict__ sums,
                                               const float* __restrict__ gamma,
                                               const float* __restrict__ beta,
                                               int n) {
    size_t idx = (size_t)blockIdx.x * 256 + threadIdx.x;
    size_t total = (size_t)n * 32;
    if (idx >= total) return;
    int cg = (int)(idx & 31);
    int c0 = cg * 4;
    float inv_n = 1.0f / (float)n;
    float4 v = ((const float4*)out)[idx];
    float4 r;
#define BN1(OUT, VIN, J)                                                   \
    {                                                                      \
        float mean = sums[c0 + J] * inv_n;                                 \
        float var  = fmaxf(sums[C + c0 + J] * inv_n - mean * mean, 0.f);   \
        float sc   = rsqrtf(var + 1e-5f) * gamma[c0 + J];                  \
        OUT = fmaxf(fmaf(VIN - mean, sc, beta[c0 + J]), 0.f);              \
    }
    BN1(r.x, v.x, 0)
    BN1(r.y, v.y, 1)
    BN1(r.z, v.z, 2)
    BN1(r.w, v.w, 3)
#undef BN1
    ((float4*)out)[idx] = r;
}

extern "C" void kernel_launch(void* const* d_in, const int* in_sizes, int n_in,
                              void* d_out, int out_size, void* d_ws, size_t ws_size,
                              hipStream_t stream) {
    const float* x     = (const float*)d_in[0];
    const int*   ei    = (const int*)d_in[1];   // [2, E]: row = ei[e], col = ei[E+e]
    const float* ew    = (const float*)d_in[2];
    const float* W     = (const float*)d_in[3];
    const float* gamma = (const float*)d_in[4];
    const float* beta  = (const float*)d_in[5];

    const int n  = in_sizes[0] / C;
    const int nE = in_sizes[2];

    const int NB    = (n + 127) >> 7;          // 128-col buckets
    const int NBLK  = (nE + 2047) / 2048;      // hist/scatter blocks
    const int scanN = NB * NBLK;
    const int scanB = (scanN + 255) / 256;
    const int gB    = (n + 63) / 64;           // gemm blocks

    float* out = (float*)d_out;
    char* p = (char*)d_ws;
#define ALLOC(TYPE, NAME, BYTES) \
    TYPE NAME = (TYPE)p; p += ((size_t)(BYTES) + 255) & ~(size_t)255;
    ALLOC(int2*,   ev2,    (size_t)nE * 8)
    ALLOC(int2*,   evs,    (size_t)nE * 8)
    ALLOC(ushort*, xb,     (size_t)n * C * 2)
    ALLOC(ushort*, aggb,   (size_t)n * C * 2)
    ALLOC(int*,    counts, (size_t)scanN * 4)
    ALLOC(int*,    bsum,   (size_t)scanB * 4)
    ALLOC(int*,    bstart, (size_t)(NB + 1) * 4)
    ALLOC(float*,  dis,    (size_t)n * 4)
    ALLOC(int*,    offs,   (size_t)(n + 1) * 4)
    ALLOC(ushort*, WbT,    32768)
    ALLOC(float*,  sums,   1024)
    ALLOC(float*,  part,   (size_t)gB * 256 * 4)
#undef ALLOC

    const long total4 = (long)n * 32;  // n*C/4

    hipMemsetAsync(sums, 0, 256 * 4, stream);

    k_hist   <<<NBLK, 256, 0, stream>>>(ei + nE, counts, nE, NB, NBLK);
    k_scan1  <<<scanB, 256, 0, stream>>>(counts, bsum, scanN);
    k_scan2  <<<1, 256, 0, stream>>>(bsum, scanB);
    k_scan3  <<<scanB, 256, 0, stream>>>(counts, bsum, bstart, scanN, NBLK, NB, nE);
    k_scatter<<<NBLK, 256, 0, stream>>>(ei, ew, counts, ev2, nE, NB, NBLK);
    k_sortdeg<<<NB, 256, 0, stream>>>(ev2, bstart, evs, offs, dis, n, nE);
    k_wcvt   <<<64, 256, 0, stream>>>(W, WbT);
    k_cvt    <<<(int)((total4 + 255) / 256), 256, 0, stream>>>((const float4*)x, dis, (ushort4*)xb, total4);
    k_segagg <<<(n + 15) / 16, 256, 0, stream>>>(xb, evs, offs, dis, aggb, n);
    k_gemm   <<<gB, 256, 0, stream>>>(aggb, out, WbT, part, n);
    k_finish <<<16, 256, 0, stream>>>(part, sums, gB);
    k_apply  <<<(int)((total4 + 255) / 256), 256, 0, stream>>>(out, sums, gamma, beta, n);
}

// Round 11
// 220.838 us; speedup vs baseline: 1.1129x; 1.1129x over previous
//
#include <hip/hip_runtime.h>

#define C 128
#define MAXNB 1024
typedef unsigned int uint;
typedef unsigned short ushort;
typedef __attribute__((ext_vector_type(4))) float f32x4;
typedef __attribute__((ext_vector_type(8))) short bf16x8;

__device__ __forceinline__ float blo(uint u) { return __uint_as_float(u << 16); }
__device__ __forceinline__ float bhi(uint u) { return __uint_as_float(u & 0xFFFF0000u); }
// pack two f32 -> (bf16(LO) | bf16(HI)<<16), round-half-up
#define PACKBF(LO, HI) __builtin_amdgcn_perm(__float_as_uint(HI) + 0x8000u, \
                                             __float_as_uint(LO) + 0x8000u, 0x07060302u)

// ---------------- A1: per-block bucket histogram (no global atomics) ----------------
__global__ __launch_bounds__(256) void k_hist(const int* __restrict__ col,
                                              int* __restrict__ counts,
                                              int nE, int NB, int NBLK) {
    __shared__ int hist[MAXNB];
    const int t = threadIdx.x, blk = blockIdx.x;
    for (int i = t; i < NB; i += 256) hist[i] = 0;
    __syncthreads();
    const int base = blk * 2048;
    for (int k = 0; k < 8; ++k) {
        int e = base + k * 256 + t;
        if (e < nE) atomicAdd(&hist[col[e] >> 7], 1);
    }
    __syncthreads();
    for (int i = t; i < NB; i += 256) counts[i * NBLK + blk] = hist[i];
}

// ---------------- exclusive scan of counts[scanN], 3 kernels ----------------
__global__ __launch_bounds__(256) void k_scan1(int* __restrict__ counts,
                                               int* __restrict__ bsum, int scanN) {
    __shared__ int s[256];
    int t = threadIdx.x;
    int i = blockIdx.x * 256 + t;
    int v = (i < scanN) ? counts[i] : 0;
    s[t] = v;
    __syncthreads();
    for (int d = 1; d < 256; d <<= 1) {
        int a = (t >= d) ? s[t - d] : 0;
        __syncthreads();
        s[t] += a;
        __syncthreads();
    }
    if (i < scanN) counts[i] = s[t] - v;
    if (t == 255) bsum[blockIdx.x] = s[255];
}

__global__ __launch_bounds__(256) void k_scan2(int* __restrict__ bsum, int nb) {
    __shared__ int s[256];
    __shared__ int carry;
    int t = threadIdx.x;
    if (t == 0) carry = 0;
    __syncthreads();
    int nch = (nb + 255) / 256;
    for (int c = 0; c < nch; ++c) {
        int i = c * 256 + t;
        int v = (i < nb) ? bsum[i] : 0;
        s[t] = v;
        __syncthreads();
        for (int d = 1; d < 256; d <<= 1) {
            int a = (t >= d) ? s[t - d] : 0;
            __syncthreads();
            s[t] += a;
            __syncthreads();
        }
        int cb = carry;
        if (i < nb) bsum[i] = s[t] - v + cb;
        int tot = s[255];
        __syncthreads();
        if (t == 0) carry = cb + tot;
        __syncthreads();
    }
}

__global__ __launch_bounds__(256) void k_scan3(int* __restrict__ counts,
                                               const int* __restrict__ bsum,
                                               int* __restrict__ bstart,
                                               int scanN, int NBLK, int NB, int nE) {
    int i = blockIdx.x * 256 + threadIdx.x;
    if (i >= scanN) return;
    int v = counts[i] + bsum[i >> 8];
    counts[i] = v;
    if (i % NBLK == 0) {
        bstart[i / NBLK] = v;
        if (i == 0) bstart[NB] = nE;
    }
}

// ---------------- A2: bin edges into bucket regions (no global atomics) ----------------
__global__ __launch_bounds__(256) void k_scatter(const int* __restrict__ ei,
                                                 const float* __restrict__ ew,
                                                 const int* __restrict__ counts,
                                                 int2* __restrict__ ev2,
                                                 int nE, int NB, int NBLK) {
    __shared__ int base_l[MAXNB];
    __shared__ int cnt_l[MAXNB];
    const int t = threadIdx.x, blk = blockIdx.x;
    for (int i = t; i < NB; i += 256) {
        base_l[i] = counts[i * NBLK + blk];
        cnt_l[i] = 0;
    }
    __syncthreads();
    const int base = blk * 2048;
    for (int k = 0; k < 8; ++k) {
        int e = base + k * 256 + t;
        if (e >= nE) continue;
        int c = ei[nE + e];
        int row = ei[e];
        int b = c >> 7;
        int pos = base_l[b] + atomicAdd(&cnt_l[b], 1);
        ev2[pos] = make_int2(((c & 127) << 25) | row, __float_as_int(ew[e]));
    }
}

// ---------------- B: per-bucket counting sort + degree ----------------
__global__ __launch_bounds__(256) void k_sortdeg(const int2* __restrict__ ev2,
                                                 const int* __restrict__ bstart,
                                                 int2* __restrict__ evs,
                                                 int* __restrict__ offs,
                                                 float* __restrict__ dis,
                                                 int n, int nE) {
    __shared__ int cnt[128];
    __shared__ float wsum[128];
    __shared__ int cur[128];
    __shared__ int sc[128];
    const int t = threadIdx.x, b = blockIdx.x;
    if (t < 128) { cnt[t] = 0; wsum[t] = 0.f; }
    __syncthreads();
    const int s = bstart[b], e = bstart[b + 1];
    for (int i = s + t; i < e; i += 256) {
        int2 E = ev2[i];
        int cl = (uint)E.x >> 25;
        atomicAdd(&cnt[cl], 1);
        atomicAdd(&wsum[cl], __int_as_float(E.y));
    }
    __syncthreads();
    if (t < 128) sc[t] = cnt[t];
    __syncthreads();
    for (int d = 1; d < 128; d <<= 1) {
        int v = 0;
        if (t < 128 && t >= d) v = sc[t - d];
        __syncthreads();
        if (t < 128) sc[t] += v;
        __syncthreads();
    }
    if (t < 128) {
        int col = (b << 7) + t;
        int base = s + sc[t] - cnt[t];
        cur[t] = base;
        if (col < n) {
            offs[col] = base;
            dis[col] = rsqrtf(1.0f + wsum[t]);
        }
    }
    if (b == 0 && t == 0) offs[n] = nE;
    __syncthreads();
    for (int i = s + t; i < e; i += 256) {
        int2 E = ev2[i];
        int cl = (uint)E.x >> 25;
        int pos = atomicAdd(&cur[cl], 1);
        evs[pos] = make_int2(E.x & 0x1FFFFFF, E.y);
    }
}

// ---------------- xb' = bf16(dis[r] * x[r]) ----------------
__global__ __launch_bounds__(256) void k_cvt(const float4* __restrict__ x4,
                                             const float* __restrict__ dis,
                                             ushort4* __restrict__ xb4, long total4) {
    long i = (long)blockIdx.x * 256 + threadIdx.x;
    if (i >= total4) return;
    float d = dis[i >> 5];
    float4 v = x4[i];
    ushort4 r;
#define RNE(OUT, F)                                                     \
    {                                                                   \
        uint u = __float_as_uint((F) * d);                              \
        OUT = (ushort)((u + 0x7FFFu + ((u >> 16) & 1u)) >> 16);         \
    }
    RNE(r.x, v.x) RNE(r.y, v.y) RNE(r.z, v.z) RNE(r.w, v.w)
#undef RNE
    xb4[i] = r;
}

// ---------------- WbT[o][k] = bf16(W[k][o]) ----------------
__global__ __launch_bounds__(256) void k_wcvt(const float* __restrict__ W,
                                              ushort* __restrict__ WbT) {
    int idx = blockIdx.x * 256 + threadIdx.x;   // 16384 total
    int k = idx >> 7, o = idx & 127;
    uint u = __float_as_uint(W[idx]);
    WbT[o * 128 + k] = (ushort)((u + 0x7FFFu + ((u >> 16) & 1u)) >> 16);
}

// ---------------- segment aggregation -> bf16 agg ----------------
// aggb[col] = bf16( dis[col] * ( xb'[col] + sum_e w_e * xb'[row_e] ) )
__global__ __launch_bounds__(256) void k_segagg(const ushort* __restrict__ xb,
                                                const int2* __restrict__ ev,
                                                const int* __restrict__ offs,
                                                const float* __restrict__ dis,
                                                ushort* __restrict__ aggb, int n) {
    const int lane = threadIdx.x & 15;   // 0..15
    const int sub  = threadIdx.x >> 4;   // 0..15
    const int col  = blockIdx.x * 16 + sub;
    if (col >= n) return;

    uint4 sv = *(const uint4*)(xb + (size_t)col * C + lane * 8);
    float acc[8] = {blo(sv.x), bhi(sv.x), blo(sv.y), bhi(sv.y),
                    blo(sv.z), bhi(sv.z), blo(sv.w), bhi(sv.w)};

    int i = offs[col];
    const int end = offs[col + 1];

#define EDGE(E, V)                                                        \
    {                                                                     \
        float nw = __int_as_float(E.y);                                   \
        acc[0] = fmaf(nw, blo(V.x), acc[0]);                              \
        acc[1] = fmaf(nw, bhi(V.x), acc[1]);                              \
        acc[2] = fmaf(nw, blo(V.y), acc[2]);                              \
        acc[3] = fmaf(nw, bhi(V.y), acc[3]);                              \
        acc[4] = fmaf(nw, blo(V.z), acc[4]);                              \
        acc[5] = fmaf(nw, bhi(V.z), acc[5]);                              \
        acc[6] = fmaf(nw, blo(V.w), acc[6]);                              \
        acc[7] = fmaf(nw, bhi(V.w), acc[7]);                              \
    }
#define GATH(K) uint4 v##K = *(const uint4*)(xb + (size_t)e##K.x * C + lane * 8);

    for (; i + 8 <= end; i += 8) {
        int2 e0 = ev[i],     e1 = ev[i + 1], e2 = ev[i + 2], e3 = ev[i + 3];
        int2 e4 = ev[i + 4], e5 = ev[i + 5], e6 = ev[i + 6], e7 = ev[i + 7];
        GATH(0) GATH(1) GATH(2) GATH(3) GATH(4) GATH(5) GATH(6) GATH(7)
        EDGE(e0, v0) EDGE(e1, v1) EDGE(e2, v2) EDGE(e3, v3)
        EDGE(e4, v4) EDGE(e5, v5) EDGE(e6, v6) EDGE(e7, v7)
    }
    for (; i + 2 <= end; i += 2) {
        int2 e0 = ev[i], e1 = ev[i + 1];
        GATH(0) GATH(1)
        EDGE(e0, v0) EDGE(e1, v1)
    }
    if (i < end) {
        int2 e0 = ev[i];
        GATH(0)
        EDGE(e0, v0)
    }
#undef GATH
#undef EDGE

    float d = dis[col];
    uint4 r;
    r.x = PACKBF(d * acc[0], d * acc[1]);
    r.y = PACKBF(d * acc[2], d * acc[3]);
    r.z = PACKBF(d * acc[4], d * acc[5]);
    r.w = PACKBF(d * acc[6], d * acc[7]);
    *(uint4*)(aggb + (size_t)col * C + lane * 8) = r;
}

// ---------------- MFMA GEMM: outb = bf16(aggb @ W) ----------------
// A = W^T tile, B = bf16 agg rows (direct 16B loads). D transposed: lane owns
// 4 consecutive channels of one row per ot. No LDS, no barriers, no atomics.
__global__ __launch_bounds__(256, 4) void k_gemm(const ushort* __restrict__ aggb,
                                                 ushort* __restrict__ outb,
                                                 const ushort* __restrict__ WbT,
                                                 int n) {
    const int t = threadIdx.x;
    const int lane = t & 63;
    const int wv = t >> 6;
    const int lr = lane & 15;
    const int lk = lane >> 4;
    const long m = (long)blockIdx.x * 64 + wv * 16 + lr;
    const bool inr = m < (long)n;

    bf16x8 b0, b1, b2, b3;
    if (inr) {
        const bf16x8* p = (const bf16x8*)(aggb + (size_t)m * C + lk * 8);
        b0 = p[0];   // k = lk*8
        b1 = p[4];   // k = 32 + lk*8
        b2 = p[8];   // k = 64 + lk*8
        b3 = p[12];  // k = 96 + lk*8
    } else {
        b0 = b1 = b2 = b3 = (bf16x8){0, 0, 0, 0, 0, 0, 0, 0};
    }

    f32x4 acc[8];
#pragma unroll
    for (int ot = 0; ot < 8; ++ot) acc[ot] = (f32x4){0.f, 0.f, 0.f, 0.f};

#pragma unroll 2
    for (int ot = 0; ot < 8; ++ot) {
        const ushort* wp = WbT + (ot * 16 + lr) * 128 + lk * 8;
        bf16x8 a0 = *(const bf16x8*)(wp);
        bf16x8 a1 = *(const bf16x8*)(wp + 32);
        bf16x8 a2 = *(const bf16x8*)(wp + 64);
        bf16x8 a3 = *(const bf16x8*)(wp + 96);
        acc[ot] = __builtin_amdgcn_mfma_f32_16x16x32_bf16(a0, b0, acc[ot], 0, 0, 0);
        acc[ot] = __builtin_amdgcn_mfma_f32_16x16x32_bf16(a1, b1, acc[ot], 0, 0, 0);
        acc[ot] = __builtin_amdgcn_mfma_f32_16x16x32_bf16(a2, b2, acc[ot], 0, 0, 0);
        acc[ot] = __builtin_amdgcn_mfma_f32_16x16x32_bf16(a3, b3, acc[ot], 0, 0, 0);
    }

    if (inr) {
        ushort* orow = outb + (size_t)m * C + lk * 4;
#pragma unroll
        for (int ot = 0; ot < 8; ++ot) {
            uint2 r;
            r.x = PACKBF(acc[ot][0], acc[ot][1]);
            r.y = PACKBF(acc[ot][2], acc[ot][3]);
            *(uint2*)(orow + ot * 16) = r;
        }
    }
}

// ---------------- BN stats from bf16 outb: per-block partials ----------------
// 1024 thr: cg = t&15 (8 channels via uint4), rl = t>>4 (64 row lanes).
__global__ __launch_bounds__(1024) void k_stats(const uint4* __restrict__ ob4,
                                                float* __restrict__ part, int n) {
    const int t = threadIdx.x;
    const int cg = t & 15;
    const int rl = t >> 4;
    float s[8] = {0, 0, 0, 0, 0, 0, 0, 0};
    float q[8] = {0, 0, 0, 0, 0, 0, 0, 0};
    for (int r = blockIdx.x * 64 + rl; r < n; r += gridDim.x * 64) {
        uint4 v = ob4[(size_t)r * 16 + cg];
        float f0 = blo(v.x), f1 = bhi(v.x), f2 = blo(v.y), f3 = bhi(v.y);
        float f4 = blo(v.z), f5 = bhi(v.z), f6 = blo(v.w), f7 = bhi(v.w);
        s[0] += f0; q[0] = fmaf(f0, f0, q[0]);
        s[1] += f1; q[1] = fmaf(f1, f1, q[1]);
        s[2] += f2; q[2] = fmaf(f2, f2, q[2]);
        s[3] += f3; q[3] = fmaf(f3, f3, q[3]);
        s[4] += f4; q[4] = fmaf(f4, f4, q[4]);
        s[5] += f5; q[5] = fmaf(f5, f5, q[5]);
        s[6] += f6; q[6] = fmaf(f6, f6, q[6]);
        s[7] += f7; q[7] = fmaf(f7, f7, q[7]);
    }
    // wave-level reduce over rl (lanes t, t+16, t+32, t+48 share cg)
#pragma unroll
    for (int j = 0; j < 8; ++j) {
        s[j] += __shfl_xor(s[j], 16); s[j] += __shfl_xor(s[j], 32);
        q[j] += __shfl_xor(q[j], 16); q[j] += __shfl_xor(q[j], 32);
    }
    __shared__ float lds_s[16][128];   // [wave][channel]
    __shared__ float lds_q[16][128];
    const int wvi = t >> 6;
    if ((t & 63) < 16) {
#pragma unroll
        for (int j = 0; j < 8; ++j) {
            lds_s[wvi][cg * 8 + j] = s[j];
            lds_q[wvi][cg * 8 + j] = q[j];
        }
    }
    __syncthreads();
    if (t < 128) {
        float ps = 0.f;
#pragma unroll
        for (int w = 0; w < 16; ++w) ps += lds_s[w][t];
        part[(size_t)blockIdx.x * 256 + t] = ps;
    } else if (t < 256) {
        int c = t - 128;
        float pq = 0.f;
#pragma unroll
        for (int w = 0; w < 16; ++w) pq += lds_q[w][c];
        part[(size_t)blockIdx.x * 256 + t] = pq;
    }
}

__global__ __launch_bounds__(256) void k_finish(const float* __restrict__ part,
                                                float* __restrict__ sums, int nblk) {
    int t = threadIdx.x;
    float s = 0.f;
    for (int b = blockIdx.x; b < nblk; b += gridDim.x) s += part[(size_t)b * 256 + t];
    atomicAdd(&sums[t], s);
}

// ---------------- BN apply + ReLU: outb (bf16) -> out (f32) ----------------
__global__ __launch_bounds__(256) void k_apply(const uint4* __restrict__ ob4,
                                               float* __restrict__ out,
                                               const float* __restrict__ sums,
                                               const float* __restrict__ gamma,
                                               const float* __restrict__ beta,
                                               int n) {
    size_t idx = (size_t)blockIdx.x * 256 + threadIdx.x;   // uint4 index (8 bf16)
    size_t total = (size_t)n * 16;
    if (idx >= total) return;
    int cg = (int)(idx & 15);
    int c0 = cg * 8;
    float inv_n = 1.0f / (float)n;
    uint4 v = ob4[idx];
    float f[8] = {blo(v.x), bhi(v.x), blo(v.y), bhi(v.y),
                  blo(v.z), bhi(v.z), blo(v.w), bhi(v.w)};
    float4 r0, r1;
#define BN1(OUT, J)                                                        \
    {                                                                      \
        float mean = sums[c0 + J] * inv_n;                                 \
        float var  = fmaxf(sums[C + c0 + J] * inv_n - mean * mean, 0.f);   \
        float sc   = rsqrtf(var + 1e-5f) * gamma[c0 + J];                  \
        OUT = fmaxf(fmaf(f[J] - mean, sc, beta[c0 + J]), 0.f);             \
    }
    BN1(r0.x, 0) BN1(r0.y, 1) BN1(r0.z, 2) BN1(r0.w, 3)
    BN1(r1.x, 4) BN1(r1.y, 5) BN1(r1.z, 6) BN1(r1.w, 7)
#undef BN1
    float4* orow = (float4*)(out + (idx >> 4) * C + c0);
    orow[0] = r0;
    orow[1] = r1;
}

extern "C" void kernel_launch(void* const* d_in, const int* in_sizes, int n_in,
                              void* d_out, int out_size, void* d_ws, size_t ws_size,
                              hipStream_t stream) {
    const float* x     = (const float*)d_in[0];
    const int*   ei    = (const int*)d_in[1];   // [2, E]: row = ei[e], col = ei[E+e]
    const float* ew    = (const float*)d_in[2];
    const float* W     = (const float*)d_in[3];
    const float* gamma = (const float*)d_in[4];
    const float* beta  = (const float*)d_in[5];

    const int n  = in_sizes[0] / C;
    const int nE = in_sizes[2];

    const int NB    = (n + 127) >> 7;          // 128-col buckets
    const int NBLK  = (nE + 2047) / 2048;      // hist/scatter blocks
    const int scanN = NB * NBLK;
    const int scanB = (scanN + 255) / 256;
    const int SB    = 256;                     // k_stats blocks

    float* out = (float*)d_out;
    char* p = (char*)d_ws;
#define ALLOC(TYPE, NAME, BYTES) \
    TYPE NAME = (TYPE)p; p += ((size_t)(BYTES) + 255) & ~(size_t)255;
    ALLOC(int2*,   ev2,    (size_t)nE * 8)
    ALLOC(int2*,   evs,    (size_t)nE * 8)
    ALLOC(ushort*, xb,     (size_t)n * C * 2)
    ALLOC(ushort*, aggb,   (size_t)n * C * 2)
    ALLOC(ushort*, outb,   (size_t)n * C * 2)
    ALLOC(int*,    counts, (size_t)scanN * 4)
    ALLOC(int*,    bsum,   (size_t)scanB * 4)
    ALLOC(int*,    bstart, (size_t)(NB + 1) * 4)
    ALLOC(float*,  dis,    (size_t)n * 4)
    ALLOC(int*,    offs,   (size_t)(n + 1) * 4)
    ALLOC(ushort*, WbT,    32768)
    ALLOC(float*,  sums,   1024)
    ALLOC(float*,  part,   (size_t)SB * 256 * 4)
#undef ALLOC

    const long total4 = (long)n * 32;   // n*C/4 (f32 float4s)
    const long totalb = (long)n * 16;   // n*C/8 (bf16 uint4s)

    hipMemsetAsync(sums, 0, 256 * 4, stream);

    k_hist   <<<NBLK, 256, 0, stream>>>(ei + nE, counts, nE, NB, NBLK);
    k_scan1  <<<scanB, 256, 0, stream>>>(counts, bsum, scanN);
    k_scan2  <<<1, 256, 0, stream>>>(bsum, scanB);
    k_scan3  <<<scanB, 256, 0, stream>>>(counts, bsum, bstart, scanN, NBLK, NB, nE);
    k_scatter<<<NBLK, 256, 0, stream>>>(ei, ew, counts, ev2, nE, NB, NBLK);
    k_sortdeg<<<NB, 256, 0, stream>>>(ev2, bstart, evs, offs, dis, n, nE);
    k_wcvt   <<<64, 256, 0, stream>>>(W, WbT);
    k_cvt    <<<(int)((total4 + 255) / 256), 256, 0, stream>>>((const float4*)x, dis, (ushort4*)xb, total4);
    k_segagg <<<(n + 15) / 16, 256, 0, stream>>>(xb, evs, offs, dis, aggb, n);
    k_gemm   <<<(n + 63) / 64, 256, 0, stream>>>(aggb, outb, WbT, n);
    k_stats  <<<SB, 1024, 0, stream>>>((const uint4*)outb, part, n);
    k_finish <<<16, 256, 0, stream>>>(part, sums, SB);
    k_apply  <<<(int)((totalb + 255) / 256), 256, 0, stream>>>((const uint4*)outb, out, sums, gamma, beta, n);
}

// Round 12
// 211.541 us; speedup vs baseline: 1.1618x; 1.0439x over previous
//
#include <hip/hip_runtime.h>

#define C 128
#define MAXNB 1024
typedef unsigned int uint;
typedef unsigned short ushort;
typedef __attribute__((ext_vector_type(4))) float f32x4;
typedef __attribute__((ext_vector_type(8))) short bf16x8;

__device__ __forceinline__ float blo(uint u) { return __uint_as_float(u << 16); }
__device__ __forceinline__ float bhi(uint u) { return __uint_as_float(u & 0xFFFF0000u); }
// pack two f32 -> (bf16(LO) | bf16(HI)<<16), round-half-up
#define PACKBF(LO, HI) __builtin_amdgcn_perm(__float_as_uint(HI) + 0x8000u, \
                                             __float_as_uint(LO) + 0x8000u, 0x07060302u)

// ---------------- A1: per-block bucket histogram (8192 edges/block) ----------------
__global__ __launch_bounds__(512) void k_hist(const int* __restrict__ col,
                                              int* __restrict__ counts,
                                              int nE, int NB, int NBLK) {
    __shared__ int hist[MAXNB];
    const int t = threadIdx.x, blk = blockIdx.x;
    for (int i = t; i < NB; i += 512) hist[i] = 0;
    __syncthreads();
    const int base = blk * 8192;
    for (int k = 0; k < 16; ++k) {
        int e = base + k * 512 + t;
        if (e < nE) atomicAdd(&hist[col[e] >> 7], 1);
    }
    __syncthreads();
    for (int i = t; i < NB; i += 512) counts[i * NBLK + blk] = hist[i];
}

// ---------------- exclusive scan of counts[scanN], 3 kernels ----------------
__global__ __launch_bounds__(256) void k_scan1(int* __restrict__ counts,
                                               int* __restrict__ bsum, int scanN) {
    __shared__ int s[256];
    int t = threadIdx.x;
    int i = blockIdx.x * 256 + t;
    int v = (i < scanN) ? counts[i] : 0;
    s[t] = v;
    __syncthreads();
    for (int d = 1; d < 256; d <<= 1) {
        int a = (t >= d) ? s[t - d] : 0;
        __syncthreads();
        s[t] += a;
        __syncthreads();
    }
    if (i < scanN) counts[i] = s[t] - v;
    if (t == 255) bsum[blockIdx.x] = s[255];
}

__global__ __launch_bounds__(256) void k_scan2(int* __restrict__ bsum, int nb) {
    __shared__ int s[256];
    __shared__ int carry;
    int t = threadIdx.x;
    if (t == 0) carry = 0;
    __syncthreads();
    int nch = (nb + 255) / 256;
    for (int c = 0; c < nch; ++c) {
        int i = c * 256 + t;
        int v = (i < nb) ? bsum[i] : 0;
        s[t] = v;
        __syncthreads();
        for (int d = 1; d < 256; d <<= 1) {
            int a = (t >= d) ? s[t - d] : 0;
            __syncthreads();
            s[t] += a;
            __syncthreads();
        }
        int cb = carry;
        if (i < nb) bsum[i] = s[t] - v + cb;
        int tot = s[255];
        __syncthreads();
        if (t == 0) carry = cb + tot;
        __syncthreads();
    }
}

__global__ __launch_bounds__(256) void k_scan3(int* __restrict__ counts,
                                               const int* __restrict__ bsum,
                                               int* __restrict__ bstart,
                                               int scanN, int NBLK, int NB, int nE) {
    int i = blockIdx.x * 256 + threadIdx.x;
    if (i >= scanN) return;
    int v = counts[i] + bsum[i >> 8];
    counts[i] = v;
    if (i % NBLK == 0) {
        bstart[i / NBLK] = v;
        if (i == 0) bstart[NB] = nE;
    }
}

// ---------------- A2: bin edges into bucket regions (8192 edges/block) ----------------
__global__ __launch_bounds__(512) void k_scatter(const int* __restrict__ ei,
                                                 const float* __restrict__ ew,
                                                 const int* __restrict__ counts,
                                                 int2* __restrict__ ev2,
                                                 int nE, int NB, int NBLK) {
    __shared__ int base_l[MAXNB];
    __shared__ int cnt_l[MAXNB];
    const int t = threadIdx.x, blk = blockIdx.x;
    for (int i = t; i < NB; i += 512) {
        base_l[i] = counts[i * NBLK + blk];
        cnt_l[i] = 0;
    }
    __syncthreads();
    const int base = blk * 8192;
    for (int k = 0; k < 16; ++k) {
        int e = base + k * 512 + t;
        if (e >= nE) continue;
        int c = ei[nE + e];
        int row = ei[e];
        int b = c >> 7;
        int pos = base_l[b] + atomicAdd(&cnt_l[b], 1);
        ev2[pos] = make_int2(((c & 127) << 25) | row, __float_as_int(ew[e]));
    }
}

// ---------------- B: per-bucket counting sort + degree ----------------
__global__ __launch_bounds__(256) void k_sortdeg(const int2* __restrict__ ev2,
                                                 const int* __restrict__ bstart,
                                                 int2* __restrict__ evs,
                                                 int* __restrict__ offs,
                                                 float* __restrict__ dis,
                                                 int n, int nE) {
    __shared__ int cnt[128];
    __shared__ float wsum[128];
    __shared__ int cur[128];
    __shared__ int sc[128];
    const int t = threadIdx.x, b = blockIdx.x;
    if (t < 128) { cnt[t] = 0; wsum[t] = 0.f; }
    __syncthreads();
    const int s = bstart[b], e = bstart[b + 1];
    for (int i = s + t; i < e; i += 256) {
        int2 E = ev2[i];
        int cl = (uint)E.x >> 25;
        atomicAdd(&cnt[cl], 1);
        atomicAdd(&wsum[cl], __int_as_float(E.y));
    }
    __syncthreads();
    if (t < 128) sc[t] = cnt[t];
    __syncthreads();
    for (int d = 1; d < 128; d <<= 1) {
        int v = 0;
        if (t < 128 && t >= d) v = sc[t - d];
        __syncthreads();
        if (t < 128) sc[t] += v;
        __syncthreads();
    }
    if (t < 128) {
        int col = (b << 7) + t;
        int base = s + sc[t] - cnt[t];
        cur[t] = base;
        if (col < n) {
            offs[col] = base;
            dis[col] = rsqrtf(1.0f + wsum[t]);
        }
    }
    if (b == 0 && t == 0) offs[n] = nE;
    __syncthreads();
    for (int i = s + t; i < e; i += 256) {
        int2 E = ev2[i];
        int cl = (uint)E.x >> 25;
        int pos = atomicAdd(&cur[cl], 1);
        evs[pos] = make_int2(E.x & 0x1FFFFFF, E.y);
    }
}

// ---------------- xb' = bf16(dis[r] * x[r]) ----------------
__global__ __launch_bounds__(256) void k_cvt(const float4* __restrict__ x4,
                                             const float* __restrict__ dis,
                                             ushort4* __restrict__ xb4, long total4) {
    long i = (long)blockIdx.x * 256 + threadIdx.x;
    if (i >= total4) return;
    float d = dis[i >> 5];
    float4 v = x4[i];
    ushort4 r;
#define RNE(OUT, F)                                                     \
    {                                                                   \
        uint u = __float_as_uint((F) * d);                              \
        OUT = (ushort)((u + 0x7FFFu + ((u >> 16) & 1u)) >> 16);         \
    }
    RNE(r.x, v.x) RNE(r.y, v.y) RNE(r.z, v.z) RNE(r.w, v.w)
#undef RNE
    xb4[i] = r;
}

// ---------------- WbT[o][k] = bf16(W[k][o]) ----------------
__global__ __launch_bounds__(256) void k_wcvt(const float* __restrict__ W,
                                              ushort* __restrict__ WbT) {
    int idx = blockIdx.x * 256 + threadIdx.x;   // 16384 total
    int k = idx >> 7, o = idx & 127;
    uint u = __float_as_uint(W[idx]);
    WbT[o * 128 + k] = (ushort)((u + 0x7FFFu + ((u >> 16) & 1u)) >> 16);
}

// ---------------- segment aggregation -> bf16 agg ----------------
// 2 cols per 16-lane group, interleaved gather streams (2 independent chains).
__global__ __launch_bounds__(256) void k_segagg(const ushort* __restrict__ xb,
                                                const int2* __restrict__ ev,
                                                const int* __restrict__ offs,
                                                const float* __restrict__ dis,
                                                ushort* __restrict__ aggb, int n) {
    const int lane = threadIdx.x & 15;   // 0..15
    const int g    = threadIdx.x >> 4;   // 0..15
    const int colA = blockIdx.x * 32 + g * 2;
    const int colB = colA + 1;
    const bool vA = colA < n, vB = colB < n;

    float accA[8] = {0.f, 0.f, 0.f, 0.f, 0.f, 0.f, 0.f, 0.f};
    float accB[8] = {0.f, 0.f, 0.f, 0.f, 0.f, 0.f, 0.f, 0.f};
    int iA = 0, eA = 0, iB = 0, eB = 0;

    if (vA) {
        uint4 sv = *(const uint4*)(xb + (size_t)colA * C + lane * 8);
        accA[0] = blo(sv.x); accA[1] = bhi(sv.x); accA[2] = blo(sv.y); accA[3] = bhi(sv.y);
        accA[4] = blo(sv.z); accA[5] = bhi(sv.z); accA[6] = blo(sv.w); accA[7] = bhi(sv.w);
        iA = offs[colA]; eA = offs[colA + 1];
    }
    if (vB) {
        uint4 sv = *(const uint4*)(xb + (size_t)colB * C + lane * 8);
        accB[0] = blo(sv.x); accB[1] = bhi(sv.x); accB[2] = blo(sv.y); accB[3] = bhi(sv.y);
        accB[4] = blo(sv.z); accB[5] = bhi(sv.z); accB[6] = blo(sv.w); accB[7] = bhi(sv.w);
        iB = offs[colB]; eB = offs[colB + 1];
    }

#define EDGE(ACC, E, V)                                                   \
    {                                                                     \
        float nw = __int_as_float(E.y);                                   \
        ACC[0] = fmaf(nw, blo(V.x), ACC[0]);                              \
        ACC[1] = fmaf(nw, bhi(V.x), ACC[1]);                              \
        ACC[2] = fmaf(nw, blo(V.y), ACC[2]);                              \
        ACC[3] = fmaf(nw, bhi(V.y), ACC[3]);                              \
        ACC[4] = fmaf(nw, blo(V.z), ACC[4]);                              \
        ACC[5] = fmaf(nw, bhi(V.z), ACC[5]);                              \
        ACC[6] = fmaf(nw, blo(V.w), ACC[6]);                              \
        ACC[7] = fmaf(nw, bhi(V.w), ACC[7]);                              \
    }
#define GATH(V, E) uint4 V = *(const uint4*)(xb + (size_t)(E).x * C + lane * 8);

    // interleaved main loop: 4 edges per col per iteration (8 gathers, 2 chains)
    while (iA + 4 <= eA && iB + 4 <= eB) {
        int2 a0 = ev[iA], a1 = ev[iA + 1], a2 = ev[iA + 2], a3 = ev[iA + 3];
        int2 b0 = ev[iB], b1 = ev[iB + 1], b2 = ev[iB + 2], b3 = ev[iB + 3];
        GATH(va0, a0) GATH(vb0, b0) GATH(va1, a1) GATH(vb1, b1)
        GATH(va2, a2) GATH(vb2, b2) GATH(va3, a3) GATH(vb3, b3)
        EDGE(accA, a0, va0) EDGE(accB, b0, vb0)
        EDGE(accA, a1, va1) EDGE(accB, b1, vb1)
        EDGE(accA, a2, va2) EDGE(accB, b2, vb2)
        EDGE(accA, a3, va3) EDGE(accB, b3, vb3)
        iA += 4; iB += 4;
    }
    // drain A
    for (; iA + 4 <= eA; iA += 4) {
        int2 a0 = ev[iA], a1 = ev[iA + 1], a2 = ev[iA + 2], a3 = ev[iA + 3];
        GATH(v0, a0) GATH(v1, a1) GATH(v2, a2) GATH(v3, a3)
        EDGE(accA, a0, v0) EDGE(accA, a1, v1) EDGE(accA, a2, v2) EDGE(accA, a3, v3)
    }
    for (; iA < eA; ++iA) {
        int2 a0 = ev[iA];
        GATH(v0, a0)
        EDGE(accA, a0, v0)
    }
    // drain B
    for (; iB + 4 <= eB; iB += 4) {
        int2 b0 = ev[iB], b1 = ev[iB + 1], b2 = ev[iB + 2], b3 = ev[iB + 3];
        GATH(v0, b0) GATH(v1, b1) GATH(v2, b2) GATH(v3, b3)
        EDGE(accB, b0, v0) EDGE(accB, b1, v1) EDGE(accB, b2, v2) EDGE(accB, b3, v3)
    }
    for (; iB < eB; ++iB) {
        int2 b0 = ev[iB];
        GATH(v0, b0)
        EDGE(accB, b0, v0)
    }
#undef GATH
#undef EDGE

    if (vA) {
        float d = dis[colA];
        uint4 r;
        r.x = PACKBF(d * accA[0], d * accA[1]);
        r.y = PACKBF(d * accA[2], d * accA[3]);
        r.z = PACKBF(d * accA[4], d * accA[5]);
        r.w = PACKBF(d * accA[6], d * accA[7]);
        *(uint4*)(aggb + (size_t)colA * C + lane * 8) = r;
    }
    if (vB) {
        float d = dis[colB];
        uint4 r;
        r.x = PACKBF(d * accB[0], d * accB[1]);
        r.y = PACKBF(d * accB[2], d * accB[3]);
        r.z = PACKBF(d * accB[4], d * accB[5]);
        r.w = PACKBF(d * accB[6], d * accB[7]);
        *(uint4*)(aggb + (size_t)colB * C + lane * 8) = r;
    }
}

// ---------------- MFMA GEMM: outb = bf16(aggb @ W) ----------------
__global__ __launch_bounds__(256, 4) void k_gemm(const ushort* __restrict__ aggb,
                                                 ushort* __restrict__ outb,
                                                 const ushort* __restrict__ WbT,
                                                 int n) {
    const int t = threadIdx.x;
    const int lane = t & 63;
    const int wv = t >> 6;
    const int lr = lane & 15;
    const int lk = lane >> 4;
    const long m = (long)blockIdx.x * 64 + wv * 16 + lr;
    const bool inr = m < (long)n;

    bf16x8 b0, b1, b2, b3;
    if (inr) {
        const bf16x8* p = (const bf16x8*)(aggb + (size_t)m * C + lk * 8);
        b0 = p[0];
        b1 = p[4];
        b2 = p[8];
        b3 = p[12];
    } else {
        b0 = b1 = b2 = b3 = (bf16x8){0, 0, 0, 0, 0, 0, 0, 0};
    }

    f32x4 acc[8];
#pragma unroll
    for (int ot = 0; ot < 8; ++ot) acc[ot] = (f32x4){0.f, 0.f, 0.f, 0.f};

#pragma unroll 2
    for (int ot = 0; ot < 8; ++ot) {
        const ushort* wp = WbT + (ot * 16 + lr) * 128 + lk * 8;
        bf16x8 a0 = *(const bf16x8*)(wp);
        bf16x8 a1 = *(const bf16x8*)(wp + 32);
        bf16x8 a2 = *(const bf16x8*)(wp + 64);
        bf16x8 a3 = *(const bf16x8*)(wp + 96);
        acc[ot] = __builtin_amdgcn_mfma_f32_16x16x32_bf16(a0, b0, acc[ot], 0, 0, 0);
        acc[ot] = __builtin_amdgcn_mfma_f32_16x16x32_bf16(a1, b1, acc[ot], 0, 0, 0);
        acc[ot] = __builtin_amdgcn_mfma_f32_16x16x32_bf16(a2, b2, acc[ot], 0, 0, 0);
        acc[ot] = __builtin_amdgcn_mfma_f32_16x16x32_bf16(a3, b3, acc[ot], 0, 0, 0);
    }

    if (inr) {
        ushort* orow = outb + (size_t)m * C + lk * 4;
#pragma unroll
        for (int ot = 0; ot < 8; ++ot) {
            uint2 r;
            r.x = PACKBF(acc[ot][0], acc[ot][1]);
            r.y = PACKBF(acc[ot][2], acc[ot][3]);
            *(uint2*)(orow + ot * 16) = r;
        }
    }
}

// ---------------- BN stats from bf16 outb: per-block partials ----------------
__global__ __launch_bounds__(1024) void k_stats(const uint4* __restrict__ ob4,
                                                float* __restrict__ part, int n) {
    const int t = threadIdx.x;
    const int cg = t & 15;
    const int rl = t >> 4;
    float s[8] = {0, 0, 0, 0, 0, 0, 0, 0};
    float q[8] = {0, 0, 0, 0, 0, 0, 0, 0};
    for (int r = blockIdx.x * 64 + rl; r < n; r += gridDim.x * 64) {
        uint4 v = ob4[(size_t)r * 16 + cg];
        float f0 = blo(v.x), f1 = bhi(v.x), f2 = blo(v.y), f3 = bhi(v.y);
        float f4 = blo(v.z), f5 = bhi(v.z), f6 = blo(v.w), f7 = bhi(v.w);
        s[0] += f0; q[0] = fmaf(f0, f0, q[0]);
        s[1] += f1; q[1] = fmaf(f1, f1, q[1]);
        s[2] += f2; q[2] = fmaf(f2, f2, q[2]);
        s[3] += f3; q[3] = fmaf(f3, f3, q[3]);
        s[4] += f4; q[4] = fmaf(f4, f4, q[4]);
        s[5] += f5; q[5] = fmaf(f5, f5, q[5]);
        s[6] += f6; q[6] = fmaf(f6, f6, q[6]);
        s[7] += f7; q[7] = fmaf(f7, f7, q[7]);
    }
#pragma unroll
    for (int j = 0; j < 8; ++j) {
        s[j] += __shfl_xor(s[j], 16); s[j] += __shfl_xor(s[j], 32);
        q[j] += __shfl_xor(q[j], 16); q[j] += __shfl_xor(q[j], 32);
    }
    __shared__ float lds_s[16][128];
    __shared__ float lds_q[16][128];
    const int wvi = t >> 6;
    if ((t & 63) < 16) {
#pragma unroll
        for (int j = 0; j < 8; ++j) {
            lds_s[wvi][cg * 8 + j] = s[j];
            lds_q[wvi][cg * 8 + j] = q[j];
        }
    }
    __syncthreads();
    if (t < 128) {
        float ps = 0.f;
#pragma unroll
        for (int w = 0; w < 16; ++w) ps += lds_s[w][t];
        part[(size_t)blockIdx.x * 256 + t] = ps;
    } else if (t < 256) {
        int c = t - 128;
        float pq = 0.f;
#pragma unroll
        for (int w = 0; w < 16; ++w) pq += lds_q[w][c];
        part[(size_t)blockIdx.x * 256 + t] = pq;
    }
}

__global__ __launch_bounds__(256) void k_finish(const float* __restrict__ part,
                                                float* __restrict__ sums, int nblk) {
    int t = threadIdx.x;
    float s = 0.f;
    for (int b = blockIdx.x; b < nblk; b += gridDim.x) s += part[(size_t)b * 256 + t];
    atomicAdd(&sums[t], s);
}

// ---------------- BN apply + ReLU: outb (bf16) -> out (f32) ----------------
__global__ __launch_bounds__(256) void k_apply(const uint4* __restrict__ ob4,
                                               float* __restrict__ out,
                                               const float* __restrict__ sums,
                                               const float* __restrict__ gamma,
                                               const float* __restrict__ beta,
                                               int n) {
    size_t idx = (size_t)blockIdx.x * 256 + threadIdx.x;   // uint4 index (8 bf16)
    size_t total = (size_t)n * 16;
    if (idx >= total) return;
    int cg = (int)(idx & 15);
    int c0 = cg * 8;
    float inv_n = 1.0f / (float)n;
    uint4 v = ob4[idx];
    float f[8] = {blo(v.x), bhi(v.x), blo(v.y), bhi(v.y),
                  blo(v.z), bhi(v.z), blo(v.w), bhi(v.w)};
    float4 r0, r1;
#define BN1(OUT, J)                                                        \
    {                                                                      \
        float mean = sums[c0 + J] * inv_n;                                 \
        float var  = fmaxf(sums[C + c0 + J] * inv_n - mean * mean, 0.f);   \
        float sc   = rsqrtf(var + 1e-5f) * gamma[c0 + J];                  \
        OUT = fmaxf(fmaf(f[J] - mean, sc, beta[c0 + J]), 0.f);             \
    }
    BN1(r0.x, 0) BN1(r0.y, 1) BN1(r0.z, 2) BN1(r0.w, 3)
    BN1(r1.x, 4) BN1(r1.y, 5) BN1(r1.z, 6) BN1(r1.w, 7)
#undef BN1
    float4* orow = (float4*)(out + (idx >> 4) * C + c0);
    orow[0] = r0;
    orow[1] = r1;
}

extern "C" void kernel_launch(void* const* d_in, const int* in_sizes, int n_in,
                              void* d_out, int out_size, void* d_ws, size_t ws_size,
                              hipStream_t stream) {
    const float* x     = (const float*)d_in[0];
    const int*   ei    = (const int*)d_in[1];   // [2, E]: row = ei[e], col = ei[E+e]
    const float* ew    = (const float*)d_in[2];
    const float* W     = (const float*)d_in[3];
    const float* gamma = (const float*)d_in[4];
    const float* beta  = (const float*)d_in[5];

    const int n  = in_sizes[0] / C;
    const int nE = in_sizes[2];

    const int NB    = (n + 127) >> 7;          // 128-col buckets
    const int NBLK  = (nE + 8191) / 8192;      // hist/scatter blocks
    const int scanN = NB * NBLK;
    const int scanB = (scanN + 255) / 256;
    const int SB    = 256;                     // k_stats blocks

    float* out = (float*)d_out;
    char* p = (char*)d_ws;
#define ALLOC(TYPE, NAME, BYTES) \
    TYPE NAME = (TYPE)p; p += ((size_t)(BYTES) + 255) & ~(size_t)255;
    ALLOC(int2*,   ev2,    (size_t)nE * 8)
    ALLOC(int2*,   evs,    (size_t)nE * 8)
    ALLOC(ushort*, xb,     (size_t)n * C * 2)
    ALLOC(ushort*, aggb,   (size_t)n * C * 2)
    ALLOC(ushort*, outb,   (size_t)n * C * 2)
    ALLOC(int*,    counts, (size_t)scanN * 4)
    ALLOC(int*,    bsum,   (size_t)scanB * 4)
    ALLOC(int*,    bstart, (size_t)(NB + 1) * 4)
    ALLOC(float*,  dis,    (size_t)n * 4)
    ALLOC(int*,    offs,   (size_t)(n + 1) * 4)
    ALLOC(ushort*, WbT,    32768)
    ALLOC(float*,  sums,   1024)
    ALLOC(float*,  part,   (size_t)SB * 256 * 4)
#undef ALLOC

    const long total4 = (long)n * 32;   // n*C/4 (f32 float4s)
    const long totalb = (long)n * 16;   // n*C/8 (bf16 uint4s)

    hipMemsetAsync(sums, 0, 256 * 4, stream);

    k_hist   <<<NBLK, 512, 0, stream>>>(ei + nE, counts, nE, NB, NBLK);
    k_scan1  <<<scanB, 256, 0, stream>>>(counts, bsum, scanN);
    k_scan2  <<<1, 256, 0, stream>>>(bsum, scanB);
    k_scan3  <<<scanB, 256, 0, stream>>>(counts, bsum, bstart, scanN, NBLK, NB, nE);
    k_scatter<<<NBLK, 512, 0, stream>>>(ei, ew, counts, ev2, nE, NB, NBLK);
    k_sortdeg<<<NB, 256, 0, stream>>>(ev2, bstart, evs, offs, dis, n, nE);
    k_wcvt   <<<64, 256, 0, stream>>>(W, WbT);
    k_cvt    <<<(int)((total4 + 255) / 256), 256, 0, stream>>>((const float4*)x, dis, (ushort4*)xb, total4);
    k_segagg <<<(n + 31) / 32, 256, 0, stream>>>(xb, evs, offs, dis, aggb, n);
    k_gemm   <<<(n + 63) / 64, 256, 0, stream>>>(aggb, outb, WbT, n);
    k_stats  <<<SB, 1024, 0, stream>>>((const uint4*)outb, part, n);
    k_finish <<<16, 256, 0, stream>>>(part, sums, SB);
    k_apply  <<<(int)((totalb + 255) / 256), 256, 0, stream>>>((const uint4*)outb, out, sums, gamma, beta, n);
}

// Round 13
// 198.862 us; speedup vs baseline: 1.2359x; 1.0638x over previous
//
#include <hip/hip_runtime.h>

#define C 128
#define MAXNB 1024
typedef unsigned int uint;
typedef unsigned short ushort;
typedef __attribute__((ext_vector_type(4))) float f32x4;
typedef __attribute__((ext_vector_type(8))) short bf16x8;

__device__ __forceinline__ float blo(uint u) { return __uint_as_float(u << 16); }
__device__ __forceinline__ float bhi(uint u) { return __uint_as_float(u & 0xFFFF0000u); }
// pack two f32 -> (bf16(LO) | bf16(HI)<<16), round-half-up
#define PACKBF(LO, HI) __builtin_amdgcn_perm(__float_as_uint(HI) + 0x8000u, \
                                             __float_as_uint(LO) + 0x8000u, 0x07060302u)

// ---------------- A1: per-block bucket histogram (8192 edges/block) ----------------
__global__ __launch_bounds__(512) void k_hist(const int* __restrict__ col,
                                              int* __restrict__ counts,
                                              int nE, int NB, int NBLK) {
    __shared__ int hist[MAXNB];
    const int t = threadIdx.x, blk = blockIdx.x;
    for (int i = t; i < NB; i += 512) hist[i] = 0;
    __syncthreads();
    const int base = blk * 8192;
    for (int k = 0; k < 16; ++k) {
        int e = base + k * 512 + t;
        if (e < nE) atomicAdd(&hist[col[e] >> 7], 1);
    }
    __syncthreads();
    for (int i = t; i < NB; i += 512) counts[i * NBLK + blk] = hist[i];
}

// ---------------- exclusive scan of counts[scanN], 2 kernels ----------------
// After scan1+scan2: global_prefix(i) = counts[i] + bsum[i>>8]  (consumers fold it in).
__global__ __launch_bounds__(256) void k_scan1(int* __restrict__ counts,
                                               int* __restrict__ bsum, int scanN) {
    __shared__ int s[256];
    int t = threadIdx.x;
    int i = blockIdx.x * 256 + t;
    int v = (i < scanN) ? counts[i] : 0;
    s[t] = v;
    __syncthreads();
    for (int d = 1; d < 256; d <<= 1) {
        int a = (t >= d) ? s[t - d] : 0;
        __syncthreads();
        s[t] += a;
        __syncthreads();
    }
    if (i < scanN) counts[i] = s[t] - v;
    if (t == 255) bsum[blockIdx.x] = s[255];
}

__global__ __launch_bounds__(256) void k_scan2(int* __restrict__ bsum, int nb) {
    __shared__ int s[256];
    __shared__ int carry;
    int t = threadIdx.x;
    if (t == 0) carry = 0;
    __syncthreads();
    int nch = (nb + 255) / 256;
    for (int c = 0; c < nch; ++c) {
        int i = c * 256 + t;
        int v = (i < nb) ? bsum[i] : 0;
        s[t] = v;
        __syncthreads();
        for (int d = 1; d < 256; d <<= 1) {
            int a = (t >= d) ? s[t - d] : 0;
            __syncthreads();
            s[t] += a;
            __syncthreads();
        }
        int cb = carry;
        if (i < nb) bsum[i] = s[t] - v + cb;
        int tot = s[255];
        __syncthreads();
        if (t == 0) carry = cb + tot;
        __syncthreads();
    }
}

// ---------------- A2: bin edges into bucket regions (8192 edges/block) ----------------
__global__ __launch_bounds__(512) void k_scatter(const int* __restrict__ ei,
                                                 const float* __restrict__ ew,
                                                 const int* __restrict__ counts,
                                                 const int* __restrict__ bsum,
                                                 int2* __restrict__ ev2,
                                                 int nE, int NB, int NBLK) {
    __shared__ int base_l[MAXNB];
    __shared__ int cnt_l[MAXNB];
    const int t = threadIdx.x, blk = blockIdx.x;
    for (int i = t; i < NB; i += 512) {
        int idx = i * NBLK + blk;
        base_l[i] = counts[idx] + bsum[idx >> 8];
        cnt_l[i] = 0;
    }
    __syncthreads();
    const int base = blk * 8192;
    for (int k = 0; k < 16; ++k) {
        int e = base + k * 512 + t;
        if (e >= nE) continue;
        int c = ei[nE + e];
        int row = ei[e];
        int b = c >> 7;
        int pos = base_l[b] + atomicAdd(&cnt_l[b], 1);
        ev2[pos] = make_int2(((c & 127) << 25) | row, __float_as_int(ew[e]));
    }
}

// ---------------- B: per-bucket counting sort + degree ----------------
__global__ __launch_bounds__(256) void k_sortdeg(const int2* __restrict__ ev2,
                                                 const int* __restrict__ counts,
                                                 const int* __restrict__ bsum,
                                                 int2* __restrict__ evs,
                                                 int* __restrict__ offs,
                                                 float* __restrict__ dis,
                                                 int n, int nE, int NB, int NBLK) {
    __shared__ int cnt[128];
    __shared__ float wsum[128];
    __shared__ int cur[128];
    __shared__ int sc[128];
    __shared__ int seg[2];
    const int t = threadIdx.x, b = blockIdx.x;
    if (t < 128) { cnt[t] = 0; wsum[t] = 0.f; }
    if (t == 0) {
        int i0 = b * NBLK;
        seg[0] = counts[i0] + bsum[i0 >> 8];
    } else if (t == 1) {
        int i1 = (b + 1) * NBLK;
        seg[1] = (b + 1 < NB) ? counts[i1] + bsum[i1 >> 8] : nE;
    }
    __syncthreads();
    const int s = seg[0], e = seg[1];
    for (int i = s + t; i < e; i += 256) {
        int2 E = ev2[i];
        int cl = (uint)E.x >> 25;
        atomicAdd(&cnt[cl], 1);
        atomicAdd(&wsum[cl], __int_as_float(E.y));
    }
    __syncthreads();
    if (t < 128) sc[t] = cnt[t];
    __syncthreads();
    for (int d = 1; d < 128; d <<= 1) {
        int v = 0;
        if (t < 128 && t >= d) v = sc[t - d];
        __syncthreads();
        if (t < 128) sc[t] += v;
        __syncthreads();
    }
    if (t < 128) {
        int col = (b << 7) + t;
        int base = s + sc[t] - cnt[t];
        cur[t] = base;
        if (col < n) {
            offs[col] = base;
            dis[col] = rsqrtf(1.0f + wsum[t]);
        }
    }
    if (b == 0 && t == 0) offs[n] = nE;
    __syncthreads();
    for (int i = s + t; i < e; i += 256) {
        int2 E = ev2[i];
        int cl = (uint)E.x >> 25;
        int pos = atomicAdd(&cur[cl], 1);
        evs[pos] = make_int2(E.x & 0x1FFFFFF, E.y);
    }
}

// ---------------- xb' = bf16(dis[r]*x[r]); tail blocks: WbT = bf16(W^T) ----------------
__global__ __launch_bounds__(256) void k_cvt(const float4* __restrict__ x4,
                                             const float* __restrict__ dis,
                                             ushort4* __restrict__ xb4,
                                             const float* __restrict__ W,
                                             ushort* __restrict__ WbT,
                                             long total4, int cvtB) {
    if ((int)blockIdx.x >= cvtB) {
        int idx = ((int)blockIdx.x - cvtB) * 256 + threadIdx.x;   // 16384 total
        int k = idx >> 7, o = idx & 127;
        uint u = __float_as_uint(W[idx]);
        WbT[o * 128 + k] = (ushort)((u + 0x7FFFu + ((u >> 16) & 1u)) >> 16);
        return;
    }
    long i = (long)blockIdx.x * 256 + threadIdx.x;
    if (i >= total4) return;
    float d = dis[i >> 5];
    float4 v = x4[i];
    ushort4 r;
#define RNE(OUT, F)                                                     \
    {                                                                   \
        uint u = __float_as_uint((F) * d);                              \
        OUT = (ushort)((u + 0x7FFFu + ((u >> 16) & 1u)) >> 16);         \
    }
    RNE(r.x, v.x) RNE(r.y, v.y) RNE(r.z, v.z) RNE(r.w, v.w)
#undef RNE
    xb4[i] = r;
}

// ---------------- segment aggregation -> bf16 agg (R11 proven form) ----------------
__global__ __launch_bounds__(256) void k_segagg(const ushort* __restrict__ xb,
                                                const int2* __restrict__ ev,
                                                const int* __restrict__ offs,
                                                const float* __restrict__ dis,
                                                ushort* __restrict__ aggb, int n) {
    const int lane = threadIdx.x & 15;   // 0..15
    const int sub  = threadIdx.x >> 4;   // 0..15
    const int col  = blockIdx.x * 16 + sub;
    if (col >= n) return;

    uint4 sv = *(const uint4*)(xb + (size_t)col * C + lane * 8);
    float acc[8] = {blo(sv.x), bhi(sv.x), blo(sv.y), bhi(sv.y),
                    blo(sv.z), bhi(sv.z), blo(sv.w), bhi(sv.w)};

    int i = offs[col];
    const int end = offs[col + 1];

#define EDGE(E, V)                                                        \
    {                                                                     \
        float nw = __int_as_float(E.y);                                   \
        acc[0] = fmaf(nw, blo(V.x), acc[0]);                              \
        acc[1] = fmaf(nw, bhi(V.x), acc[1]);                              \
        acc[2] = fmaf(nw, blo(V.y), acc[2]);                              \
        acc[3] = fmaf(nw, bhi(V.y), acc[3]);                              \
        acc[4] = fmaf(nw, blo(V.z), acc[4]);                              \
        acc[5] = fmaf(nw, bhi(V.z), acc[5]);                              \
        acc[6] = fmaf(nw, blo(V.w), acc[6]);                              \
        acc[7] = fmaf(nw, bhi(V.w), acc[7]);                              \
    }
#define GATH(K) uint4 v##K = *(const uint4*)(xb + (size_t)e##K.x * C + lane * 8);

    for (; i + 8 <= end; i += 8) {
        int2 e0 = ev[i],     e1 = ev[i + 1], e2 = ev[i + 2], e3 = ev[i + 3];
        int2 e4 = ev[i + 4], e5 = ev[i + 5], e6 = ev[i + 6], e7 = ev[i + 7];
        GATH(0) GATH(1) GATH(2) GATH(3) GATH(4) GATH(5) GATH(6) GATH(7)
        EDGE(e0, v0) EDGE(e1, v1) EDGE(e2, v2) EDGE(e3, v3)
        EDGE(e4, v4) EDGE(e5, v5) EDGE(e6, v6) EDGE(e7, v7)
    }
    for (; i + 2 <= end; i += 2) {
        int2 e0 = ev[i], e1 = ev[i + 1];
        GATH(0) GATH(1)
        EDGE(e0, v0) EDGE(e1, v1)
    }
    if (i < end) {
        int2 e0 = ev[i];
        GATH(0)
        EDGE(e0, v0)
    }
#undef GATH
#undef EDGE

    float d = dis[col];
    uint4 r;
    r.x = PACKBF(d * acc[0], d * acc[1]);
    r.y = PACKBF(d * acc[2], d * acc[3]);
    r.z = PACKBF(d * acc[4], d * acc[5]);
    r.w = PACKBF(d * acc[6], d * acc[7]);
    *(uint4*)(aggb + (size_t)col * C + lane * 8) = r;
}

// ---------------- MFMA GEMM: outb = bf16(aggb @ W) ----------------
__global__ __launch_bounds__(256, 4) void k_gemm(const ushort* __restrict__ aggb,
                                                 ushort* __restrict__ outb,
                                                 const ushort* __restrict__ WbT,
                                                 int n) {
    const int t = threadIdx.x;
    const int lane = t & 63;
    const int wv = t >> 6;
    const int lr = lane & 15;
    const int lk = lane >> 4;
    const long m = (long)blockIdx.x * 64 + wv * 16 + lr;
    const bool inr = m < (long)n;

    bf16x8 b0, b1, b2, b3;
    if (inr) {
        const bf16x8* p = (const bf16x8*)(aggb + (size_t)m * C + lk * 8);
        b0 = p[0];
        b1 = p[4];
        b2 = p[8];
        b3 = p[12];
    } else {
        b0 = b1 = b2 = b3 = (bf16x8){0, 0, 0, 0, 0, 0, 0, 0};
    }

    f32x4 acc[8];
#pragma unroll
    for (int ot = 0; ot < 8; ++ot) acc[ot] = (f32x4){0.f, 0.f, 0.f, 0.f};

#pragma unroll 2
    for (int ot = 0; ot < 8; ++ot) {
        const ushort* wp = WbT + (ot * 16 + lr) * 128 + lk * 8;
        bf16x8 a0 = *(const bf16x8*)(wp);
        bf16x8 a1 = *(const bf16x8*)(wp + 32);
        bf16x8 a2 = *(const bf16x8*)(wp + 64);
        bf16x8 a3 = *(const bf16x8*)(wp + 96);
        acc[ot] = __builtin_amdgcn_mfma_f32_16x16x32_bf16(a0, b0, acc[ot], 0, 0, 0);
        acc[ot] = __builtin_amdgcn_mfma_f32_16x16x32_bf16(a1, b1, acc[ot], 0, 0, 0);
        acc[ot] = __builtin_amdgcn_mfma_f32_16x16x32_bf16(a2, b2, acc[ot], 0, 0, 0);
        acc[ot] = __builtin_amdgcn_mfma_f32_16x16x32_bf16(a3, b3, acc[ot], 0, 0, 0);
    }

    if (inr) {
        ushort* orow = outb + (size_t)m * C + lk * 4;
#pragma unroll
        for (int ot = 0; ot < 8; ++ot) {
            uint2 r;
            r.x = PACKBF(acc[ot][0], acc[ot][1]);
            r.y = PACKBF(acc[ot][2], acc[ot][3]);
            *(uint2*)(orow + ot * 16) = r;
        }
    }
}

// ---------------- BN stats from bf16 outb: per-block partials ----------------
__global__ __launch_bounds__(1024) void k_stats(const uint4* __restrict__ ob4,
                                                float* __restrict__ part, int n) {
    const int t = threadIdx.x;
    const int cg = t & 15;
    const int rl = t >> 4;
    float s[8] = {0, 0, 0, 0, 0, 0, 0, 0};
    float q[8] = {0, 0, 0, 0, 0, 0, 0, 0};
    for (int r = blockIdx.x * 64 + rl; r < n; r += gridDim.x * 64) {
        uint4 v = ob4[(size_t)r * 16 + cg];
        float f0 = blo(v.x), f1 = bhi(v.x), f2 = blo(v.y), f3 = bhi(v.y);
        float f4 = blo(v.z), f5 = bhi(v.z), f6 = blo(v.w), f7 = bhi(v.w);
        s[0] += f0; q[0] = fmaf(f0, f0, q[0]);
        s[1] += f1; q[1] = fmaf(f1, f1, q[1]);
        s[2] += f2; q[2] = fmaf(f2, f2, q[2]);
        s[3] += f3; q[3] = fmaf(f3, f3, q[3]);
        s[4] += f4; q[4] = fmaf(f4, f4, q[4]);
        s[5] += f5; q[5] = fmaf(f5, f5, q[5]);
        s[6] += f6; q[6] = fmaf(f6, f6, q[6]);
        s[7] += f7; q[7] = fmaf(f7, f7, q[7]);
    }
#pragma unroll
    for (int j = 0; j < 8; ++j) {
        s[j] += __shfl_xor(s[j], 16); s[j] += __shfl_xor(s[j], 32);
        q[j] += __shfl_xor(q[j], 16); q[j] += __shfl_xor(q[j], 32);
    }
    __shared__ float lds_s[16][128];
    __shared__ float lds_q[16][128];
    const int wvi = t >> 6;
    if ((t & 63) < 16) {
#pragma unroll
        for (int j = 0; j < 8; ++j) {
            lds_s[wvi][cg * 8 + j] = s[j];
            lds_q[wvi][cg * 8 + j] = q[j];
        }
    }
    __syncthreads();
    if (t < 128) {
        float ps = 0.f;
#pragma unroll
        for (int w = 0; w < 16; ++w) ps += lds_s[w][t];
        part[(size_t)blockIdx.x * 256 + t] = ps;
    } else if (t < 256) {
        int c = t - 128;
        float pq = 0.f;
#pragma unroll
        for (int w = 0; w < 16; ++w) pq += lds_q[w][c];
        part[(size_t)blockIdx.x * 256 + t] = pq;
    }
}

__global__ __launch_bounds__(256) void k_finish(const float* __restrict__ part,
                                                float* __restrict__ sums, int nblk) {
    int t = threadIdx.x;
    float s = 0.f;
    for (int b = blockIdx.x; b < nblk; b += gridDim.x) s += part[(size_t)b * 256 + t];
    atomicAdd(&sums[t], s);
}

// ---------------- BN apply + ReLU: outb (bf16) -> out (f32) ----------------
__global__ __launch_bounds__(256) void k_apply(const uint4* __restrict__ ob4,
                                               float* __restrict__ out,
                                               const float* __restrict__ sums,
                                               const float* __restrict__ gamma,
                                               const float* __restrict__ beta,
                                               int n) {
    size_t idx = (size_t)blockIdx.x * 256 + threadIdx.x;   // uint4 index (8 bf16)
    size_t total = (size_t)n * 16;
    if (idx >= total) return;
    int cg = (int)(idx & 15);
    int c0 = cg * 8;
    float inv_n = 1.0f / (float)n;
    uint4 v = ob4[idx];
    float f[8] = {blo(v.x), bhi(v.x), blo(v.y), bhi(v.y),
                  blo(v.z), bhi(v.z), blo(v.w), bhi(v.w)};
    float4 r0, r1;
#define BN1(OUT, J)                                                        \
    {                                                                      \
        float mean = sums[c0 + J] * inv_n;                                 \
        float var  = fmaxf(sums[C + c0 + J] * inv_n - mean * mean, 0.f);   \
        float sc   = rsqrtf(var + 1e-5f) * gamma[c0 + J];                  \
        OUT = fmaxf(fmaf(f[J] - mean, sc, beta[c0 + J]), 0.f);             \
    }
    BN1(r0.x, 0) BN1(r0.y, 1) BN1(r0.z, 2) BN1(r0.w, 3)
    BN1(r1.x, 4) BN1(r1.y, 5) BN1(r1.z, 6) BN1(r1.w, 7)
#undef BN1
    float4* orow = (float4*)(out + (idx >> 4) * C + c0);
    orow[0] = r0;
    orow[1] = r1;
}

extern "C" void kernel_launch(void* const* d_in, const int* in_sizes, int n_in,
                              void* d_out, int out_size, void* d_ws, size_t ws_size,
                              hipStream_t stream) {
    const float* x     = (const float*)d_in[0];
    const int*   ei    = (const int*)d_in[1];   // [2, E]: row = ei[e], col = ei[E+e]
    const float* ew    = (const float*)d_in[2];
    const float* W     = (const float*)d_in[3];
    const float* gamma = (const float*)d_in[4];
    const float* beta  = (const float*)d_in[5];

    const int n  = in_sizes[0] / C;
    const int nE = in_sizes[2];

    const int NB    = (n + 127) >> 7;          // 128-col buckets
    const int NBLK  = (nE + 8191) / 8192;      // hist/scatter blocks
    const int scanN = NB * NBLK;
    const int scanB = (scanN + 255) / 256;
    const int SB    = 256;                     // k_stats blocks

    float* out = (float*)d_out;
    char* p = (char*)d_ws;
#define ALLOC(TYPE, NAME, BYTES) \
    TYPE NAME = (TYPE)p; p += ((size_t)(BYTES) + 255) & ~(size_t)255;
    ALLOC(int2*,   ev2,    (size_t)nE * 8)
    ALLOC(int2*,   evs,    (size_t)nE * 8)
    ALLOC(ushort*, xb,     (size_t)n * C * 2)
    ALLOC(ushort*, aggb,   (size_t)n * C * 2)
    ALLOC(ushort*, outb,   (size_t)n * C * 2)
    ALLOC(int*,    counts, (size_t)scanN * 4)
    ALLOC(int*,    bsum,   (size_t)scanB * 4)
    ALLOC(float*,  dis,    (size_t)n * 4)
    ALLOC(int*,    offs,   (size_t)(n + 1) * 4)
    ALLOC(ushort*, WbT,    32768)
    ALLOC(float*,  sums,   1024)
    ALLOC(float*,  part,   (size_t)SB * 256 * 4)
#undef ALLOC

    const long total4 = (long)n * 32;   // n*C/4 (f32 float4s)
    const long totalb = (long)n * 16;   // n*C/8 (bf16 uint4s)
    const int  cvtB   = (int)((total4 + 255) / 256);

    hipMemsetAsync(sums, 0, 256 * 4, stream);

    k_hist   <<<NBLK, 512, 0, stream>>>(ei + nE, counts, nE, NB, NBLK);
    k_scan1  <<<scanB, 256, 0, stream>>>(counts, bsum, scanN);
    k_scan2  <<<1, 256, 0, stream>>>(bsum, scanB);
    k_scatter<<<NBLK, 512, 0, stream>>>(ei, ew, counts, bsum, ev2, nE, NB, NBLK);
    k_sortdeg<<<NB, 256, 0, stream>>>(ev2, counts, bsum, evs, offs, dis, n, nE, NB, NBLK);
    k_cvt    <<<cvtB + 64, 256, 0, stream>>>((const float4*)x, dis, (ushort4*)xb, W, WbT, total4, cvtB);
    k_segagg <<<(n + 15) / 16, 256, 0, stream>>>(xb, evs, offs, dis, aggb, n);
    k_gemm   <<<(n + 63) / 64, 256, 0, stream>>>(aggb, outb, WbT, n);
    k_stats  <<<SB, 1024, 0, stream>>>((const uint4*)outb, part, n);
    k_finish <<<16, 256, 0, stream>>>(part, sums, SB);
    k_apply  <<<(int)((totalb + 255) / 256), 256, 0, stream>>>((const uint4*)outb, out, sums, gamma, beta, n);
}

// Round 14
// 195.540 us; speedup vs baseline: 1.2569x; 1.0170x over previous
//
#include <hip/hip_runtime.h>

#define C 128
#define MAXNB 1024
#define CAP 4096
typedef unsigned int uint;
typedef unsigned short ushort;
typedef __attribute__((ext_vector_type(4))) float f32x4;
typedef __attribute__((ext_vector_type(8))) short bf16x8;

__device__ __forceinline__ float blo(uint u) { return __uint_as_float(u << 16); }
__device__ __forceinline__ float bhi(uint u) { return __uint_as_float(u & 0xFFFF0000u); }
// pack two f32 -> (bf16(LO) | bf16(HI)<<16), round-half-up
#define PACKBF(LO, HI) __builtin_amdgcn_perm(__float_as_uint(HI) + 0x8000u, \
                                             __float_as_uint(LO) + 0x8000u, 0x07060302u)

// ---------------- A1: per-block bucket histogram (8192 edges/block) ----------------
__global__ __launch_bounds__(512) void k_hist(const int* __restrict__ col,
                                              int* __restrict__ counts,
                                              int nE, int NB, int NBLK) {
    __shared__ int hist[MAXNB];
    const int t = threadIdx.x, blk = blockIdx.x;
    for (int i = t; i < NB; i += 512) hist[i] = 0;
    __syncthreads();
    const int base = blk * 8192;
    for (int k = 0; k < 16; ++k) {
        int e = base + k * 512 + t;
        if (e < nE) atomicAdd(&hist[col[e] >> 7], 1);
    }
    __syncthreads();
    for (int i = t; i < NB; i += 512) counts[i * NBLK + blk] = hist[i];
}

// ---------------- exclusive scan of counts[scanN], 2 kernels ----------------
// global_prefix(i) = counts[i] + bsum[i>>8]  (consumers fold it in).
__global__ __launch_bounds__(256) void k_scan1(int* __restrict__ counts,
                                               int* __restrict__ bsum, int scanN) {
    __shared__ int s[256];
    int t = threadIdx.x;
    int i = blockIdx.x * 256 + t;
    int v = (i < scanN) ? counts[i] : 0;
    s[t] = v;
    __syncthreads();
    for (int d = 1; d < 256; d <<= 1) {
        int a = (t >= d) ? s[t - d] : 0;
        __syncthreads();
        s[t] += a;
        __syncthreads();
    }
    if (i < scanN) counts[i] = s[t] - v;
    if (t == 255) bsum[blockIdx.x] = s[255];
}

__global__ __launch_bounds__(256) void k_scan2(int* __restrict__ bsum, int nb) {
    __shared__ int s[256];
    __shared__ int carry;
    int t = threadIdx.x;
    if (t == 0) carry = 0;
    __syncthreads();
    int nch = (nb + 255) / 256;
    for (int c = 0; c < nch; ++c) {
        int i = c * 256 + t;
        int v = (i < nb) ? bsum[i] : 0;
        s[t] = v;
        __syncthreads();
        for (int d = 1; d < 256; d <<= 1) {
            int a = (t >= d) ? s[t - d] : 0;
            __syncthreads();
            s[t] += a;
            __syncthreads();
        }
        int cb = carry;
        if (i < nb) bsum[i] = s[t] - v + cb;
        int tot = s[255];
        __syncthreads();
        if (t == 0) carry = cb + tot;
        __syncthreads();
    }
}

// ---------------- A2: bin edges into bucket regions (8192 edges/block) ----------------
__global__ __launch_bounds__(512) void k_scatter(const int* __restrict__ ei,
                                                 const float* __restrict__ ew,
                                                 const int* __restrict__ counts,
                                                 const int* __restrict__ bsum,
                                                 int2* __restrict__ ev2,
                                                 int nE, int NB, int NBLK) {
    __shared__ int base_l[MAXNB];
    __shared__ int cnt_l[MAXNB];
    const int t = threadIdx.x, blk = blockIdx.x;
    for (int i = t; i < NB; i += 512) {
        int idx = i * NBLK + blk;
        base_l[i] = counts[idx] + bsum[idx >> 8];
        cnt_l[i] = 0;
    }
    __syncthreads();
    const int base = blk * 8192;
    for (int k = 0; k < 16; ++k) {
        int e = base + k * 512 + t;
        if (e >= nE) continue;
        int c = ei[nE + e];
        int row = ei[e];
        int b = c >> 7;
        int pos = base_l[b] + atomicAdd(&cnt_l[b], 1);
        ev2[pos] = make_int2(((c & 127) << 25) | row, __float_as_int(ew[e]));
    }
}

// ---------------- B1: per-bucket degree -> dis (single pass over ev2) ----------------
__global__ __launch_bounds__(256) void k_deg(const int2* __restrict__ ev2,
                                             const int* __restrict__ counts,
                                             const int* __restrict__ bsum,
                                             float* __restrict__ dis,
                                             int n, int nE, int NB, int NBLK) {
    __shared__ float wsum[128];
    __shared__ int seg[2];
    const int t = threadIdx.x, b = blockIdx.x;
    if (t < 128) wsum[t] = 0.f;
    if (t == 0) { int i0 = b * NBLK; seg[0] = counts[i0] + bsum[i0 >> 8]; }
    if (t == 1) { int i1 = (b + 1) * NBLK; seg[1] = (b + 1 < NB) ? counts[i1] + bsum[i1 >> 8] : nE; }
    __syncthreads();
    const int s = seg[0], e = seg[1];
    for (int i = s + t; i < e; i += 256) {
        int2 E = ev2[i];
        atomicAdd(&wsum[(uint)E.x >> 25], __int_as_float(E.y));
    }
    __syncthreads();
    int col = (b << 7) + t;
    if (t < 128 && col < n) dis[col] = rsqrtf(1.0f + wsum[t]);
}

// ---------------- xb' = bf16(dis[r]*x[r]); tail blocks: WbT = bf16(W^T) ----------------
__global__ __launch_bounds__(256) void k_cvt(const float4* __restrict__ x4,
                                             const float* __restrict__ dis,
                                             ushort4* __restrict__ xb4,
                                             const float* __restrict__ W,
                                             ushort* __restrict__ WbT,
                                             long total4, int cvtB) {
    if ((int)blockIdx.x >= cvtB) {
        int idx = ((int)blockIdx.x - cvtB) * 256 + threadIdx.x;   // 16384 total
        int k = idx >> 7, o = idx & 127;
        uint u = __float_as_uint(W[idx]);
        WbT[o * 128 + k] = (ushort)((u + 0x7FFFu + ((u >> 16) & 1u)) >> 16);
        return;
    }
    long i = (long)blockIdx.x * 256 + threadIdx.x;
    if (i >= total4) return;
    float d = dis[i >> 5];
    float4 v = x4[i];
    ushort4 r;
#define RNE(OUT, F)                                                     \
    {                                                                   \
        uint u = __float_as_uint((F) * d);                              \
        OUT = (ushort)((u + 0x7FFFu + ((u >> 16) & 1u)) >> 16);         \
    }
    RNE(r.x, v.x) RNE(r.y, v.y) RNE(r.z, v.z) RNE(r.w, v.w)
#undef RNE
    xb4[i] = r;
}

// ---------------- B2: fused per-bucket sort (LDS) + segment aggregation ----------------
// Block = one 128-col bucket. Phase A: stage bucket edges in registers, count per
// col, scan, ticket -> col-sorted LDS list. Phase B: 16 groups x 8 cols, gather.
__global__ __launch_bounds__(256) void k_segagg(const ushort* __restrict__ xb,
                                                const int2* __restrict__ ev2,
                                                const int* __restrict__ counts,
                                                const int* __restrict__ bsum,
                                                const float* __restrict__ dis,
                                                ushort* __restrict__ aggb,
                                                int n, int nE, int NB, int NBLK) {
    __shared__ int2 se[CAP];        // 32 KB sorted edges
    __shared__ int cnt[128];
    __shared__ int sc[128];
    __shared__ int cur[128];
    __shared__ int seg[2];
    const int t = threadIdx.x, b = blockIdx.x;
    if (t < 128) cnt[t] = 0;
    if (t == 0) { int i0 = b * NBLK; seg[0] = counts[i0] + bsum[i0 >> 8]; }
    if (t == 1) { int i1 = (b + 1) * NBLK; seg[1] = (b + 1 < NB) ? counts[i1] + bsum[i1 >> 8] : nE; }
    __syncthreads();
    const int s = seg[0], e = seg[1];
    const int m = e - s;
    const bool fits = (m <= CAP);   // block-uniform

    if (fits) {
        int2 held[16];
        // stage + count (fully unrolled -> compile-time indices, no scratch)
#pragma unroll
        for (int r = 0; r < 16; ++r) {
            int idx = r * 256 + t;
            held[r] = make_int2(0, 0);
            if (idx < m) {
                held[r] = ev2[s + idx];
                atomicAdd(&cnt[(uint)held[r].x >> 25], 1);
            }
        }
        __syncthreads();
        if (t < 128) sc[t] = cnt[t];
        __syncthreads();
        for (int d = 1; d < 128; d <<= 1) {
            int v = 0;
            if (t < 128 && t >= d) v = sc[t - d];
            __syncthreads();
            if (t < 128) sc[t] += v;
            __syncthreads();
        }
        if (t < 128) cur[t] = sc[t] - cnt[t];   // local exclusive offset
        __syncthreads();
#pragma unroll
        for (int r = 0; r < 16; ++r) {
            int idx = r * 256 + t;
            if (idx < m) {
                int cl = (uint)held[r].x >> 25;
                int pos = atomicAdd(&cur[cl], 1);
                se[pos] = make_int2(held[r].x & 0x1FFFFFF, held[r].y);
            }
        }
        __syncthreads();
    }

    // ---- phase B: 16 groups x 8 cols, no barriers below ----
    const int lane = t & 15;
    const int g = t >> 4;

#define EDGE(E, V)                                                        \
    {                                                                     \
        float nw = __int_as_float(E.y);                                   \
        acc[0] = fmaf(nw, blo(V.x), acc[0]);                              \
        acc[1] = fmaf(nw, bhi(V.x), acc[1]);                              \
        acc[2] = fmaf(nw, blo(V.y), acc[2]);                              \
        acc[3] = fmaf(nw, bhi(V.y), acc[3]);                              \
        acc[4] = fmaf(nw, blo(V.z), acc[4]);                              \
        acc[5] = fmaf(nw, bhi(V.z), acc[5]);                              \
        acc[6] = fmaf(nw, blo(V.w), acc[6]);                              \
        acc[7] = fmaf(nw, bhi(V.w), acc[7]);                              \
    }
#define GATH(K) uint4 v##K = *(const uint4*)(xb + (size_t)e##K.x * C + lane * 8);

    for (int cc = 0; cc < 8; ++cc) {
        const int cl = g * 8 + cc;
        const int col = (b << 7) + cl;
        if (col >= n) continue;

        uint4 sv = *(const uint4*)(xb + (size_t)col * C + lane * 8);
        float acc[8] = {blo(sv.x), bhi(sv.x), blo(sv.y), bhi(sv.y),
                        blo(sv.z), bhi(sv.z), blo(sv.w), bhi(sv.w)};

        if (fits) {
            int i = sc[cl] - cnt[cl];
            const int end2 = sc[cl];
            for (; i + 8 <= end2; i += 8) {
                int2 e0 = se[i],     e1 = se[i + 1], e2 = se[i + 2], e3 = se[i + 3];
                int2 e4 = se[i + 4], e5 = se[i + 5], e6 = se[i + 6], e7 = se[i + 7];
                GATH(0) GATH(1) GATH(2) GATH(3) GATH(4) GATH(5) GATH(6) GATH(7)
                EDGE(e0, v0) EDGE(e1, v1) EDGE(e2, v2) EDGE(e3, v3)
                EDGE(e4, v4) EDGE(e5, v5) EDGE(e6, v6) EDGE(e7, v7)
            }
            for (; i + 2 <= end2; i += 2) {
                int2 e0 = se[i], e1 = se[i + 1];
                GATH(0) GATH(1)
                EDGE(e0, v0) EDGE(e1, v1)
            }
            if (i < end2) {
                int2 e0 = se[i];
                GATH(0)
                EDGE(e0, v0)
            }
        } else {
            // overflow fallback (statistically never): filter-scan the bucket range
            for (int i = s; i < e; ++i) {
                int2 E = ev2[i];
                if ((int)((uint)E.x >> 25) == cl) {
                    int2 e0 = make_int2(E.x & 0x1FFFFFF, E.y);
                    GATH(0)
                    EDGE(e0, v0)
                }
            }
        }

        float d = dis[col];
        uint4 r;
        r.x = PACKBF(d * acc[0], d * acc[1]);
        r.y = PACKBF(d * acc[2], d * acc[3]);
        r.z = PACKBF(d * acc[4], d * acc[5]);
        r.w = PACKBF(d * acc[6], d * acc[7]);
        *(uint4*)(aggb + (size_t)col * C + lane * 8) = r;
    }
#undef GATH
#undef EDGE
}

// ---------------- MFMA GEMM: outb = bf16(aggb @ W) ----------------
__global__ __launch_bounds__(256, 4) void k_gemm(const ushort* __restrict__ aggb,
                                                 ushort* __restrict__ outb,
                                                 const ushort* __restrict__ WbT,
                                                 int n) {
    const int t = threadIdx.x;
    const int lane = t & 63;
    const int wv = t >> 6;
    const int lr = lane & 15;
    const int lk = lane >> 4;
    const long m = (long)blockIdx.x * 64 + wv * 16 + lr;
    const bool inr = m < (long)n;

    bf16x8 b0, b1, b2, b3;
    if (inr) {
        const bf16x8* p = (const bf16x8*)(aggb + (size_t)m * C + lk * 8);
        b0 = p[0];
        b1 = p[4];
        b2 = p[8];
        b3 = p[12];
    } else {
        b0 = b1 = b2 = b3 = (bf16x8){0, 0, 0, 0, 0, 0, 0, 0};
    }

    f32x4 acc[8];
#pragma unroll
    for (int ot = 0; ot < 8; ++ot) acc[ot] = (f32x4){0.f, 0.f, 0.f, 0.f};

#pragma unroll 2
    for (int ot = 0; ot < 8; ++ot) {
        const ushort* wp = WbT + (ot * 16 + lr) * 128 + lk * 8;
        bf16x8 a0 = *(const bf16x8*)(wp);
        bf16x8 a1 = *(const bf16x8*)(wp + 32);
        bf16x8 a2 = *(const bf16x8*)(wp + 64);
        bf16x8 a3 = *(const bf16x8*)(wp + 96);
        acc[ot] = __builtin_amdgcn_mfma_f32_16x16x32_bf16(a0, b0, acc[ot], 0, 0, 0);
        acc[ot] = __builtin_amdgcn_mfma_f32_16x16x32_bf16(a1, b1, acc[ot], 0, 0, 0);
        acc[ot] = __builtin_amdgcn_mfma_f32_16x16x32_bf16(a2, b2, acc[ot], 0, 0, 0);
        acc[ot] = __builtin_amdgcn_mfma_f32_16x16x32_bf16(a3, b3, acc[ot], 0, 0, 0);
    }

    if (inr) {
        ushort* orow = outb + (size_t)m * C + lk * 4;
#pragma unroll
        for (int ot = 0; ot < 8; ++ot) {
            uint2 r;
            r.x = PACKBF(acc[ot][0], acc[ot][1]);
            r.y = PACKBF(acc[ot][2], acc[ot][3]);
            *(uint2*)(orow + ot * 16) = r;
        }
    }
}

// ---------------- BN stats from bf16 outb: per-block partials ----------------
__global__ __launch_bounds__(1024) void k_stats(const uint4* __restrict__ ob4,
                                                float* __restrict__ part, int n) {
    const int t = threadIdx.x;
    const int cg = t & 15;
    const int rl = t >> 4;
    float s[8] = {0, 0, 0, 0, 0, 0, 0, 0};
    float q[8] = {0, 0, 0, 0, 0, 0, 0, 0};
    for (int r = blockIdx.x * 64 + rl; r < n; r += gridDim.x * 64) {
        uint4 v = ob4[(size_t)r * 16 + cg];
        float f0 = blo(v.x), f1 = bhi(v.x), f2 = blo(v.y), f3 = bhi(v.y);
        float f4 = blo(v.z), f5 = bhi(v.z), f6 = blo(v.w), f7 = bhi(v.w);
        s[0] += f0; q[0] = fmaf(f0, f0, q[0]);
        s[1] += f1; q[1] = fmaf(f1, f1, q[1]);
        s[2] += f2; q[2] = fmaf(f2, f2, q[2]);
        s[3] += f3; q[3] = fmaf(f3, f3, q[3]);
        s[4] += f4; q[4] = fmaf(f4, f4, q[4]);
        s[5] += f5; q[5] = fmaf(f5, f5, q[5]);
        s[6] += f6; q[6] = fmaf(f6, f6, q[6]);
        s[7] += f7; q[7] = fmaf(f7, f7, q[7]);
    }
#pragma unroll
    for (int j = 0; j < 8; ++j) {
        s[j] += __shfl_xor(s[j], 16); s[j] += __shfl_xor(s[j], 32);
        q[j] += __shfl_xor(q[j], 16); q[j] += __shfl_xor(q[j], 32);
    }
    __shared__ float lds_s[16][128];
    __shared__ float lds_q[16][128];
    const int wvi = t >> 6;
    if ((t & 63) < 16) {
#pragma unroll
        for (int j = 0; j < 8; ++j) {
            lds_s[wvi][cg * 8 + j] = s[j];
            lds_q[wvi][cg * 8 + j] = q[j];
        }
    }
    __syncthreads();
    if (t < 128) {
        float ps = 0.f;
#pragma unroll
        for (int w = 0; w < 16; ++w) ps += lds_s[w][t];
        part[(size_t)blockIdx.x * 256 + t] = ps;
    } else if (t < 256) {
        int c = t - 128;
        float pq = 0.f;
#pragma unroll
        for (int w = 0; w < 16; ++w) pq += lds_q[w][c];
        part[(size_t)blockIdx.x * 256 + t] = pq;
    }
}

__global__ __launch_bounds__(256) void k_finish(const float* __restrict__ part,
                                                float* __restrict__ sums, int nblk) {
    int t = threadIdx.x;
    float s = 0.f;
    for (int b = blockIdx.x; b < nblk; b += gridDim.x) s += part[(size_t)b * 256 + t];
    atomicAdd(&sums[t], s);
}

// ---------------- BN apply + ReLU: outb (bf16) -> out (f32) ----------------
__global__ __launch_bounds__(256) void k_apply(const uint4* __restrict__ ob4,
                                               float* __restrict__ out,
                                               const float* __restrict__ sums,
                                               const float* __restrict__ gamma,
                                               const float* __restrict__ beta,
                                               int n) {
    size_t idx = (size_t)blockIdx.x * 256 + threadIdx.x;   // uint4 index (8 bf16)
    size_t total = (size_t)n * 16;
    if (idx >= total) return;
    int cg = (int)(idx & 15);
    int c0 = cg * 8;
    float inv_n = 1.0f / (float)n;
    uint4 v = ob4[idx];
    float f[8] = {blo(v.x), bhi(v.x), blo(v.y), bhi(v.y),
                  blo(v.z), bhi(v.z), blo(v.w), bhi(v.w)};
    float4 r0, r1;
#define BN1(OUT, J)                                                        \
    {                                                                      \
        float mean = sums[c0 + J] * inv_n;                                 \
        float var  = fmaxf(sums[C + c0 + J] * inv_n - mean * mean, 0.f);   \
        float sc   = rsqrtf(var + 1e-5f) * gamma[c0 + J];                  \
        OUT = fmaxf(fmaf(f[J] - mean, sc, beta[c0 + J]), 0.f);             \
    }
    BN1(r0.x, 0) BN1(r0.y, 1) BN1(r0.z, 2) BN1(r0.w, 3)
    BN1(r1.x, 4) BN1(r1.y, 5) BN1(r1.z, 6) BN1(r1.w, 7)
#undef BN1
    float4* orow = (float4*)(out + (idx >> 4) * C + c0);
    orow[0] = r0;
    orow[1] = r1;
}

extern "C" void kernel_launch(void* const* d_in, const int* in_sizes, int n_in,
                              void* d_out, int out_size, void* d_ws, size_t ws_size,
                              hipStream_t stream) {
    const float* x     = (const float*)d_in[0];
    const int*   ei    = (const int*)d_in[1];   // [2, E]: row = ei[e], col = ei[E+e]
    const float* ew    = (const float*)d_in[2];
    const float* W     = (const float*)d_in[3];
    const float* gamma = (const float*)d_in[4];
    const float* beta  = (const float*)d_in[5];

    const int n  = in_sizes[0] / C;
    const int nE = in_sizes[2];

    const int NB    = (n + 127) >> 7;          // 128-col buckets
    const int NBLK  = (nE + 8191) / 8192;      // hist/scatter blocks
    const int scanN = NB * NBLK;
    const int scanB = (scanN + 255) / 256;
    const int SB    = 256;                     // k_stats blocks

    float* out = (float*)d_out;
    char* p = (char*)d_ws;
#define ALLOC(TYPE, NAME, BYTES) \
    TYPE NAME = (TYPE)p; p += ((size_t)(BYTES) + 255) & ~(size_t)255;
    ALLOC(int2*,   ev2,    (size_t)nE * 8)
    ALLOC(ushort*, xb,     (size_t)n * C * 2)
    ALLOC(ushort*, aggb,   (size_t)n * C * 2)
    ALLOC(ushort*, outb,   (size_t)n * C * 2)
    ALLOC(int*,    counts, (size_t)scanN * 4)
    ALLOC(int*,    bsum,   (size_t)scanB * 4)
    ALLOC(float*,  dis,    (size_t)n * 4)
    ALLOC(ushort*, WbT,    32768)
    ALLOC(float*,  sums,   1024)
    ALLOC(float*,  part,   (size_t)SB * 256 * 4)
#undef ALLOC

    const long total4 = (long)n * 32;   // n*C/4 (f32 float4s)
    const long totalb = (long)n * 16;   // n*C/8 (bf16 uint4s)
    const int  cvtB   = (int)((total4 + 255) / 256);

    hipMemsetAsync(sums, 0, 256 * 4, stream);

    k_hist   <<<NBLK, 512, 0, stream>>>(ei + nE, counts, nE, NB, NBLK);
    k_scan1  <<<scanB, 256, 0, stream>>>(counts, bsum, scanN);
    k_scan2  <<<1, 256, 0, stream>>>(bsum, scanB);
    k_scatter<<<NBLK, 512, 0, stream>>>(ei, ew, counts, bsum, ev2, nE, NB, NBLK);
    k_deg    <<<NB, 256, 0, stream>>>(ev2, counts, bsum, dis, n, nE, NB, NBLK);
    k_cvt    <<<cvtB + 64, 256, 0, stream>>>((const float4*)x, dis, (ushort4*)xb, W, WbT, total4, cvtB);
    k_segagg <<<NB, 256, 0, stream>>>(xb, ev2, counts, bsum, dis, aggb, n, nE, NB, NBLK);
    k_gemm   <<<(n + 63) / 64, 256, 0, stream>>>(aggb, outb, WbT, n);
    k_stats  <<<SB, 1024, 0, stream>>>((const uint4*)outb, part, n);
    k_finish <<<16, 256, 0, stream>>>(part, sums, SB);
    k_apply  <<<(int)((totalb + 255) / 256), 256, 0, stream>>>((const uint4*)outb, out, sums, gamma, beta, n);
}

// Round 16
// 194.008 us; speedup vs baseline: 1.2668x; 1.0079x over previous
//
#include <hip/hip_runtime.h>

#define C 128
#define MAXNB 1024
#define CAP 4096
typedef unsigned int uint;
typedef unsigned short ushort;
typedef __attribute__((ext_vector_type(4))) float f32x4;
typedef __attribute__((ext_vector_type(8))) short bf16x8;

__device__ __forceinline__ float blo(uint u) { return __uint_as_float(u << 16); }
__device__ __forceinline__ float bhi(uint u) { return __uint_as_float(u & 0xFFFF0000u); }
// pack two f32 -> (bf16(LO) | bf16(HI)<<16), round-half-up
#define PACKBF(LO, HI) __builtin_amdgcn_perm(__float_as_uint(HI) + 0x8000u, \
                                             __float_as_uint(LO) + 0x8000u, 0x07060302u)

// ---------------- A1: per-block bucket histogram (8192 edges/block) ----------------
__global__ __launch_bounds__(512) void k_hist(const int* __restrict__ col,
                                              int* __restrict__ counts,
                                              int nE, int NB, int NBLK) {
    __shared__ int hist[MAXNB];
    const int t = threadIdx.x, blk = blockIdx.x;
    for (int i = t; i < NB; i += 512) hist[i] = 0;
    __syncthreads();
    const int base = blk * 8192;
    for (int k = 0; k < 16; ++k) {
        int e = base + k * 512 + t;
        if (e < nE) atomicAdd(&hist[col[e] >> 7], 1);
    }
    __syncthreads();
    for (int i = t; i < NB; i += 512) counts[i * NBLK + blk] = hist[i];
}

// ---------------- exclusive scan of counts[scanN], 2 kernels ----------------
// global_prefix(i) = counts[i] + bsum[i>>8]  (consumers fold it in).
__global__ __launch_bounds__(256) void k_scan1(int* __restrict__ counts,
                                               int* __restrict__ bsum, int scanN) {
    __shared__ int s[256];
    int t = threadIdx.x;
    int i = blockIdx.x * 256 + t;
    int v = (i < scanN) ? counts[i] : 0;
    s[t] = v;
    __syncthreads();
    for (int d = 1; d < 256; d <<= 1) {
        int a = (t >= d) ? s[t - d] : 0;
        __syncthreads();
        s[t] += a;
        __syncthreads();
    }
    if (i < scanN) counts[i] = s[t] - v;
    if (t == 255) bsum[blockIdx.x] = s[255];
}

__global__ __launch_bounds__(256) void k_scan2(int* __restrict__ bsum, int nb) {
    __shared__ int s[256];
    __shared__ int carry;
    int t = threadIdx.x;
    if (t == 0) carry = 0;
    __syncthreads();
    int nch = (nb + 255) / 256;
    for (int c = 0; c < nch; ++c) {
        int i = c * 256 + t;
        int v = (i < nb) ? bsum[i] : 0;
        s[t] = v;
        __syncthreads();
        for (int d = 1; d < 256; d <<= 1) {
            int a = (t >= d) ? s[t - d] : 0;
            __syncthreads();
            s[t] += a;
            __syncthreads();
        }
        int cb = carry;
        if (i < nb) bsum[i] = s[t] - v + cb;
        int tot = s[255];
        __syncthreads();
        if (t == 0) carry = cb + tot;
        __syncthreads();
    }
}

// ---------------- A2: bin edges into bucket regions (8192 edges/block) ----------------
__global__ __launch_bounds__(512) void k_scatter(const int* __restrict__ ei,
                                                 const float* __restrict__ ew,
                                                 const int* __restrict__ counts,
                                                 const int* __restrict__ bsum,
                                                 int2* __restrict__ ev2,
                                                 int nE, int NB, int NBLK) {
    __shared__ int base_l[MAXNB];
    __shared__ int cnt_l[MAXNB];
    const int t = threadIdx.x, blk = blockIdx.x;
    for (int i = t; i < NB; i += 512) {
        int idx = i * NBLK + blk;
        base_l[i] = counts[idx] + bsum[idx >> 8];
        cnt_l[i] = 0;
    }
    __syncthreads();
    const int base = blk * 8192;
    for (int k = 0; k < 16; ++k) {
        int e = base + k * 512 + t;
        if (e >= nE) continue;
        int c = ei[nE + e];
        int row = ei[e];
        int b = c >> 7;
        int pos = base_l[b] + atomicAdd(&cnt_l[b], 1);
        ev2[pos] = make_int2(((c & 127) << 25) | row, __float_as_int(ew[e]));
    }
}

// ---------------- B1: per-bucket degree -> dis (single pass over ev2) ----------------
__global__ __launch_bounds__(256) void k_deg(const int2* __restrict__ ev2,
                                             const int* __restrict__ counts,
                                             const int* __restrict__ bsum,
                                             float* __restrict__ dis,
                                             int n, int nE, int NB, int NBLK) {
    __shared__ float wsum[128];
    __shared__ int seg[2];
    const int t = threadIdx.x, b = blockIdx.x;
    if (t < 128) wsum[t] = 0.f;
    if (t == 0) { int i0 = b * NBLK; seg[0] = counts[i0] + bsum[i0 >> 8]; }
    if (t == 1) { int i1 = (b + 1) * NBLK; seg[1] = (b + 1 < NB) ? counts[i1] + bsum[i1 >> 8] : nE; }
    __syncthreads();
    const int s = seg[0], e = seg[1];
    for (int i = s + t; i < e; i += 256) {
        int2 E = ev2[i];
        atomicAdd(&wsum[(uint)E.x >> 25], __int_as_float(E.y));
    }
    __syncthreads();
    int col = (b << 7) + t;
    if (t < 128 && col < n) dis[col] = rsqrtf(1.0f + wsum[t]);
}

// ---------------- xb' = bf16(dis[r]*x[r]); tail blocks: WbT = bf16(W^T) ----------------
__global__ __launch_bounds__(256) void k_cvt(const float4* __restrict__ x4,
                                             const float* __restrict__ dis,
                                             ushort4* __restrict__ xb4,
                                             const float* __restrict__ W,
                                             ushort* __restrict__ WbT,
                                             long total4, int cvtB) {
    if ((int)blockIdx.x >= cvtB) {
        int idx = ((int)blockIdx.x - cvtB) * 256 + threadIdx.x;   // 16384 total
        int k = idx >> 7, o = idx & 127;
        uint u = __float_as_uint(W[idx]);
        WbT[o * 128 + k] = (ushort)((u + 0x7FFFu + ((u >> 16) & 1u)) >> 16);
        return;
    }
    long i = (long)blockIdx.x * 256 + threadIdx.x;
    if (i >= total4) return;
    float d = dis[i >> 5];
    float4 v = x4[i];
    ushort4 r;
#define RNE(OUT, F)                                                     \
    {                                                                   \
        uint u = __float_as_uint((F) * d);                              \
        OUT = (ushort)((u + 0x7FFFu + ((u >> 16) & 1u)) >> 16);         \
    }
    RNE(r.x, v.x) RNE(r.y, v.y) RNE(r.z, v.z) RNE(r.w, v.w)
#undef RNE
    xb4[i] = r;
}

// ---------------- B2: fused per-bucket sort (LDS) + segment aggregation ----------------
// Block = one 128-col bucket. Phase A: stage bucket edges in registers, count per
// col, scan, ticket -> col-sorted LDS list. Phase B: 16 groups x 8 cols, gather.
__global__ __launch_bounds__(256) void k_segagg(const ushort* __restrict__ xb,
                                                const int2* __restrict__ ev2,
                                                const int* __restrict__ counts,
                                                const int* __restrict__ bsum,
                                                const float* __restrict__ dis,
                                                ushort* __restrict__ aggb,
                                                int n, int nE, int NB, int NBLK) {
    __shared__ int2 se[CAP];        // 32 KB sorted edges
    __shared__ int cnt[128];
    __shared__ int sc[128];
    __shared__ int cur[128];
    __shared__ int seg[2];
    const int t = threadIdx.x, b = blockIdx.x;
    if (t < 128) cnt[t] = 0;
    if (t == 0) { int i0 = b * NBLK; seg[0] = counts[i0] + bsum[i0 >> 8]; }
    if (t == 1) { int i1 = (b + 1) * NBLK; seg[1] = (b + 1 < NB) ? counts[i1] + bsum[i1 >> 8] : nE; }
    __syncthreads();
    const int s = seg[0], e = seg[1];
    const int m = e - s;
    const bool fits = (m <= CAP);   // block-uniform

    if (fits) {
        int2 held[16];
        // stage + count (fully unrolled -> compile-time indices, no scratch)
#pragma unroll
        for (int r = 0; r < 16; ++r) {
            int idx = r * 256 + t;
            held[r] = make_int2(0, 0);
            if (idx < m) {
                held[r] = ev2[s + idx];
                atomicAdd(&cnt[(uint)held[r].x >> 25], 1);
            }
        }
        __syncthreads();
        if (t < 128) sc[t] = cnt[t];
        __syncthreads();
        for (int d = 1; d < 128; d <<= 1) {
            int v = 0;
            if (t < 128 && t >= d) v = sc[t - d];
            __syncthreads();
            if (t < 128) sc[t] += v;
            __syncthreads();
        }
        if (t < 128) cur[t] = sc[t] - cnt[t];   // local exclusive offset
        __syncthreads();
#pragma unroll
        for (int r = 0; r < 16; ++r) {
            int idx = r * 256 + t;
            if (idx < m) {
                int cl = (uint)held[r].x >> 25;
                int pos = atomicAdd(&cur[cl], 1);
                se[pos] = make_int2(held[r].x & 0x1FFFFFF, held[r].y);
            }
        }
        __syncthreads();
    }

    // ---- phase B: 16 groups x 8 cols, no barriers below ----
    const int lane = t & 15;
    const int g = t >> 4;

#define EDGE(E, V)                                                        \
    {                                                                     \
        float nw = __int_as_float(E.y);                                   \
        acc[0] = fmaf(nw, blo(V.x), acc[0]);                              \
        acc[1] = fmaf(nw, bhi(V.x), acc[1]);                              \
        acc[2] = fmaf(nw, blo(V.y), acc[2]);                              \
        acc[3] = fmaf(nw, bhi(V.y), acc[3]);                              \
        acc[4] = fmaf(nw, blo(V.z), acc[4]);                              \
        acc[5] = fmaf(nw, bhi(V.z), acc[5]);                              \
        acc[6] = fmaf(nw, blo(V.w), acc[6]);                              \
        acc[7] = fmaf(nw, bhi(V.w), acc[7]);                              \
    }
#define GATH(K) uint4 v##K = *(const uint4*)(xb + (size_t)e##K.x * C + lane * 8);

    for (int cc = 0; cc < 8; ++cc) {
        const int cl = g * 8 + cc;
        const int col = (b << 7) + cl;
        if (col >= n) continue;

        uint4 sv = *(const uint4*)(xb + (size_t)col * C + lane * 8);
        float acc[8] = {blo(sv.x), bhi(sv.x), blo(sv.y), bhi(sv.y),
                        blo(sv.z), bhi(sv.z), blo(sv.w), bhi(sv.w)};

        if (fits) {
            int i = sc[cl] - cnt[cl];
            const int end2 = sc[cl];
            for (; i + 8 <= end2; i += 8) {
                int2 e0 = se[i],     e1 = se[i + 1], e2 = se[i + 2], e3 = se[i + 3];
                int2 e4 = se[i + 4], e5 = se[i + 5], e6 = se[i + 6], e7 = se[i + 7];
                GATH(0) GATH(1) GATH(2) GATH(3) GATH(4) GATH(5) GATH(6) GATH(7)
                EDGE(e0, v0) EDGE(e1, v1) EDGE(e2, v2) EDGE(e3, v3)
                EDGE(e4, v4) EDGE(e5, v5) EDGE(e6, v6) EDGE(e7, v7)
            }
            for (; i + 2 <= end2; i += 2) {
                int2 e0 = se[i], e1 = se[i + 1];
                GATH(0) GATH(1)
                EDGE(e0, v0) EDGE(e1, v1)
            }
            if (i < end2) {
                int2 e0 = se[i];
                GATH(0)
                EDGE(e0, v0)
            }
        } else {
            // overflow fallback (statistically never): filter-scan the bucket range
            for (int i = s; i < e; ++i) {
                int2 E = ev2[i];
                if ((int)((uint)E.x >> 25) == cl) {
                    int2 e0 = make_int2(E.x & 0x1FFFFFF, E.y);
                    GATH(0)
                    EDGE(e0, v0)
                }
            }
        }

        float d = dis[col];
        uint4 r;
        r.x = PACKBF(d * acc[0], d * acc[1]);
        r.y = PACKBF(d * acc[2], d * acc[3]);
        r.z = PACKBF(d * acc[4], d * acc[5]);
        r.w = PACKBF(d * acc[6], d * acc[7]);
        *(uint4*)(aggb + (size_t)col * C + lane * 8) = r;
    }
#undef GATH
#undef EDGE
}

// ---------------- MFMA GEMM: outb = bf16(aggb @ W) ----------------
__global__ __launch_bounds__(256, 4) void k_gemm(const ushort* __restrict__ aggb,
                                                 ushort* __restrict__ outb,
                                                 const ushort* __restrict__ WbT,
                                                 int n) {
    const int t = threadIdx.x;
    const int lane = t & 63;
    const int wv = t >> 6;
    const int lr = lane & 15;
    const int lk = lane >> 4;
    const long m = (long)blockIdx.x * 64 + wv * 16 + lr;
    const bool inr = m < (long)n;

    bf16x8 b0, b1, b2, b3;
    if (inr) {
        const bf16x8* p = (const bf16x8*)(aggb + (size_t)m * C + lk * 8);
        b0 = p[0];
        b1 = p[4];
        b2 = p[8];
        b3 = p[12];
    } else {
        b0 = b1 = b2 = b3 = (bf16x8){0, 0, 0, 0, 0, 0, 0, 0};
    }

    f32x4 acc[8];
#pragma unroll
    for (int ot = 0; ot < 8; ++ot) acc[ot] = (f32x4){0.f, 0.f, 0.f, 0.f};

#pragma unroll 2
    for (int ot = 0; ot < 8; ++ot) {
        const ushort* wp = WbT + (ot * 16 + lr) * 128 + lk * 8;
        bf16x8 a0 = *(const bf16x8*)(wp);
        bf16x8 a1 = *(const bf16x8*)(wp + 32);
        bf16x8 a2 = *(const bf16x8*)(wp + 64);
        bf16x8 a3 = *(const bf16x8*)(wp + 96);
        acc[ot] = __builtin_amdgcn_mfma_f32_16x16x32_bf16(a0, b0, acc[ot], 0, 0, 0);
        acc[ot] = __builtin_amdgcn_mfma_f32_16x16x32_bf16(a1, b1, acc[ot], 0, 0, 0);
        acc[ot] = __builtin_amdgcn_mfma_f32_16x16x32_bf16(a2, b2, acc[ot], 0, 0, 0);
        acc[ot] = __builtin_amdgcn_mfma_f32_16x16x32_bf16(a3, b3, acc[ot], 0, 0, 0);
    }

    if (inr) {
        ushort* orow = outb + (size_t)m * C + lk * 4;
#pragma unroll
        for (int ot = 0; ot < 8; ++ot) {
            uint2 r;
            r.x = PACKBF(acc[ot][0], acc[ot][1]);
            r.y = PACKBF(acc[ot][2], acc[ot][3]);
            *(uint2*)(orow + ot * 16) = r;
        }
    }
}

// ---------------- BN stats from bf16 outb: per-block partials ----------------
__global__ __launch_bounds__(1024) void k_stats(const uint4* __restrict__ ob4,
                                                float* __restrict__ part, int n) {
    const int t = threadIdx.x;
    const int cg = t & 15;
    const int rl = t >> 4;
    float s[8] = {0, 0, 0, 0, 0, 0, 0, 0};
    float q[8] = {0, 0, 0, 0, 0, 0, 0, 0};
    for (int r = blockIdx.x * 64 + rl; r < n; r += gridDim.x * 64) {
        uint4 v = ob4[(size_t)r * 16 + cg];
        float f0 = blo(v.x), f1 = bhi(v.x), f2 = blo(v.y), f3 = bhi(v.y);
        float f4 = blo(v.z), f5 = bhi(v.z), f6 = blo(v.w), f7 = bhi(v.w);
        s[0] += f0; q[0] = fmaf(f0, f0, q[0]);
        s[1] += f1; q[1] = fmaf(f1, f1, q[1]);
        s[2] += f2; q[2] = fmaf(f2, f2, q[2]);
        s[3] += f3; q[3] = fmaf(f3, f3, q[3]);
        s[4] += f4; q[4] = fmaf(f4, f4, q[4]);
        s[5] += f5; q[5] = fmaf(f5, f5, q[5]);
        s[6] += f6; q[6] = fmaf(f6, f6, q[6]);
        s[7] += f7; q[7] = fmaf(f7, f7, q[7]);
    }
#pragma unroll
    for (int j = 0; j < 8; ++j) {
        s[j] += __shfl_xor(s[j], 16); s[j] += __shfl_xor(s[j], 32);
        q[j] += __shfl_xor(q[j], 16); q[j] += __shfl_xor(q[j], 32);
    }
    __shared__ float lds_s[16][128];
    __shared__ float lds_q[16][128];
    const int wvi = t >> 6;
    if ((t & 63) < 16) {
#pragma unroll
        for (int j = 0; j < 8; ++j) {
            lds_s[wvi][cg * 8 + j] = s[j];
            lds_q[wvi][cg * 8 + j] = q[j];
        }
    }
    __syncthreads();
    if (t < 128) {
        float ps = 0.f;
#pragma unroll
        for (int w = 0; w < 16; ++w) ps += lds_s[w][t];
        part[(size_t)blockIdx.x * 256 + t] = ps;
    } else if (t < 256) {
        int c = t - 128;
        float pq = 0.f;
#pragma unroll
        for (int w = 0; w < 16; ++w) pq += lds_q[w][c];
        part[(size_t)blockIdx.x * 256 + t] = pq;
    }
}

__global__ __launch_bounds__(256) void k_finish(const float* __restrict__ part,
                                                float* __restrict__ sums, int nblk) {
    int t = threadIdx.x;
    float s = 0.f;
    for (int b = blockIdx.x; b < nblk; b += gridDim.x) s += part[(size_t)b * 256 + t];
    atomicAdd(&sums[t], s);
}

// ---------------- BN apply + ReLU: outb (bf16) -> out (f32) ----------------
__global__ __launch_bounds__(256) void k_apply(const uint4* __restrict__ ob4,
                                               float* __restrict__ out,
                                               const float* __restrict__ sums,
                                               const float* __restrict__ gamma,
                                               const float* __restrict__ beta,
                                               int n) {
    size_t idx = (size_t)blockIdx.x * 256 + threadIdx.x;   // uint4 index (8 bf16)
    size_t total = (size_t)n * 16;
    if (idx >= total) return;
    int cg = (int)(idx & 15);
    int c0 = cg * 8;
    float inv_n = 1.0f / (float)n;
    uint4 v = ob4[idx];
    float f[8] = {blo(v.x), bhi(v.x), blo(v.y), bhi(v.y),
                  blo(v.z), bhi(v.z), blo(v.w), bhi(v.w)};
    float4 r0, r1;
#define BN1(OUT, J)                                                        \
    {                                                                      \
        float mean = sums[c0 + J] * inv_n;                                 \
        float var  = fmaxf(sums[C + c0 + J] * inv_n - mean * mean, 0.f);   \
        float sc   = rsqrtf(var + 1e-5f) * gamma[c0 + J];                  \
        OUT = fmaxf(fmaf(f[J] - mean, sc, beta[c0 + J]), 0.f);             \
    }
    BN1(r0.x, 0) BN1(r0.y, 1) BN1(r0.z, 2) BN1(r0.w, 3)
    BN1(r1.x, 4) BN1(r1.y, 5) BN1(r1.z, 6) BN1(r1.w, 7)
#undef BN1
    float4* orow = (float4*)(out + (idx >> 4) * C + c0);
    orow[0] = r0;
    orow[1] = r1;
}

extern "C" void kernel_launch(void* const* d_in, const int* in_sizes, int n_in,
                              void* d_out, int out_size, void* d_ws, size_t ws_size,
                              hipStream_t stream) {
    const float* x     = (const float*)d_in[0];
    const int*   ei    = (const int*)d_in[1];   // [2, E]: row = ei[e], col = ei[E+e]
    const float* ew    = (const float*)d_in[2];
    const float* W     = (const float*)d_in[3];
    const float* gamma = (const float*)d_in[4];
    const float* beta  = (const float*)d_in[5];

    const int n  = in_sizes[0] / C;
    const int nE = in_sizes[2];

    const int NB    = (n + 127) >> 7;          // 128-col buckets
    const int NBLK  = (nE + 8191) / 8192;      // hist/scatter blocks
    const int scanN = NB * NBLK;
    const int scanB = (scanN + 255) / 256;
    const int SB    = 256;                     // k_stats blocks

    float* out = (float*)d_out;
    char* p = (char*)d_ws;
#define ALLOC(TYPE, NAME, BYTES) \
    TYPE NAME = (TYPE)p; p += ((size_t)(BYTES) + 255) & ~(size_t)255;
    ALLOC(int2*,   ev2,    (size_t)nE * 8)
    ALLOC(ushort*, xb,     (size_t)n * C * 2)
    ALLOC(ushort*, aggb,   (size_t)n * C * 2)
    ALLOC(ushort*, outb,   (size_t)n * C * 2)
    ALLOC(int*,    counts, (size_t)scanN * 4)
    ALLOC(int*,    bsum,   (size_t)scanB * 4)
    ALLOC(float*,  dis,    (size_t)n * 4)
    ALLOC(ushort*, WbT,    32768)
    ALLOC(float*,  sums,   1024)
    ALLOC(float*,  part,   (size_t)SB * 256 * 4)
#undef ALLOC

    const long total4 = (long)n * 32;   // n*C/4 (f32 float4s)
    const long totalb = (long)n * 16;   // n*C/8 (bf16 uint4s)
    const int  cvtB   = (int)((total4 + 255) / 256);

    hipMemsetAsync(sums, 0, 256 * 4, stream);

    k_hist   <<<NBLK, 512, 0, stream>>>(ei + nE, counts, nE, NB, NBLK);
    k_scan1  <<<scanB, 256, 0, stream>>>(counts, bsum, scanN);
    k_scan2  <<<1, 256, 0, stream>>>(bsum, scanB);
    k_scatter<<<NBLK, 512, 0, stream>>>(ei, ew, counts, bsum, ev2, nE, NB, NBLK);
    k_deg    <<<NB, 256, 0, stream>>>(ev2, counts, bsum, dis, n, nE, NB, NBLK);
    k_cvt    <<<cvtB + 64, 256, 0, stream>>>((const float4*)x, dis, (ushort4*)xb, W, WbT, total4, cvtB);
    k_segagg <<<NB, 256, 0, stream>>>(xb, ev2, counts, bsum, dis, aggb, n, nE, NB, NBLK);
    k_gemm   <<<(n + 63) / 64, 256, 0, stream>>>(aggb, outb, WbT, n);
    k_stats  <<<SB, 1024, 0, stream>>>((const uint4*)outb, part, n);
    k_finish <<<16, 256, 0, stream>>>(part, sums, SB);
    k_apply  <<<(int)((totalb + 255) / 256), 256, 0, stream>>>((const uint4*)outb, out, sums, gamma, beta, n);
}